// Round 14
// baseline (1535.401 us; speedup 1.0000x reference)
//
#include <hip/hip_runtime.h>

typedef unsigned short u16;
typedef unsigned int   u32;
typedef unsigned char  u8;
typedef __attribute__((ext_vector_type(8))) short bf16x8;
typedef __attribute__((ext_vector_type(4))) float f32x4;

#define DEV __device__ __forceinline__

static constexpr float SCALE = 0.044194173824159216f; // 1/sqrt(512)

DEV u16 f2bf(float f) {
  u32 u = __float_as_uint(f);
  u32 r = (u + 0x7fffu + ((u >> 16) & 1u)) >> 16;
  return (u16)r;
}
DEV float bf2f(u16 v) { u32 u = (u32)v << 16; return __uint_as_float(u); }

DEV void gl_lds16(const void* g, void* l) {
  __builtin_amdgcn_global_load_lds(
      (__attribute__((address_space(1))) void*)(void*)g,
      (__attribute__((address_space(3))) void*)l, 16, 0, 0);
}

// ---------------- convert x, masked_x -> bf16 ----------------
__global__ void k_convert(const float* __restrict__ x, const float* __restrict__ mx,
                          u16* __restrict__ xbf, u16* __restrict__ mxbf) {
  const u32 stride = gridDim.x * blockDim.x;
  for (u32 idx = blockIdx.x * blockDim.x + threadIdx.x; idx < 2u * 1048576u; idx += stride) {
    const u32 t = idx >> 20;
    const u32 i = idx & 1048575u;
    const float4 v = t ? ((const float4*)mx)[i] : ((const float4*)x)[i];
    ushort4 o;
    o.x = f2bf(v.x); o.y = f2bf(v.y); o.z = f2bf(v.z); o.w = f2bf(v.w);
    ((ushort4*)(t ? mxbf : xbf))[i] = o;
  }
}

// ---------------- weight transpose (fp32 [k][o] -> bf16 [o][k]) ----------------
struct WtransJobs { const float* src[4]; u16* dst[4]; };

__global__ void k_wtrans(WtransJobs jobs) {
  __shared__ float tile[32][33];
  const int j  = blockIdx.z;
  const float* src = jobs.src[j];
  u16* dst = jobs.dst[j];
  const int o0 = blockIdx.x * 32;
  const int k0 = blockIdx.y * 32;
  const int tx = threadIdx.x, ty = threadIdx.y;   // (32,8)
#pragma unroll
  for (int yy = 0; yy < 4; ++yy)
    tile[ty + yy * 8][tx] = src[(size_t)(k0 + ty + yy * 8) * 512 + (o0 + tx)];
  __syncthreads();
#pragma unroll
  for (int yy = 0; yy < 4; ++yy)
    dst[(size_t)(o0 + ty + yy * 8) * 512 + (k0 + tx)] = f2bf(tile[tx][ty + yy * 8]);
}

// ---------------- adjacency layout detector ----------------
__global__ void k_adjdetect(const u8* __restrict__ adj, u32* __restrict__ flag) {
  u32 cnt = 0;
  const u32 stride = gridDim.x * blockDim.x;
  for (u32 i = blockIdx.x * blockDim.x + threadIdx.x; i < (1u << 22); i += stride)
    if ((i & 3u) && adj[i]) cnt++;
#pragma unroll
  for (int m = 1; m <= 32; m <<= 1) cnt += __shfl_xor(cnt, m);
  if ((threadIdx.x & 63) == 0 && cnt) atomicAdd(flag, cnt);
}

// ---------------- adjacency -> bitmask words (dual layout) ----------------
__global__ void k_adjbits(const u8* __restrict__ adj, const u32* __restrict__ flag,
                          u32* __restrict__ adjb) {
  const int row = blockIdx.x;
  const int w = threadIdx.x;              // 256 words per row
  u32 res = 0;
  if (*flag > 100u) {                     // byte layout
    const uint4* p = (const uint4*)(adj + (size_t)row * 8192 + w * 32);
#pragma unroll
    for (int i = 0; i < 2; ++i) {
      const uint4 q = p[i];
      const u32 vs[4] = {q.x, q.y, q.z, q.w};
#pragma unroll
      for (int jj = 0; jj < 4; ++jj) {
        const u32 v = vs[jj];
        const int base = i * 16 + jj * 4;
        res |= ((v & 0x000000FFu) ? 1u : 0u) << (base + 0);
        res |= ((v & 0x0000FF00u) ? 1u : 0u) << (base + 1);
        res |= ((v & 0x00FF0000u) ? 1u : 0u) << (base + 2);
        res |= ((v & 0xFF000000u) ? 1u : 0u) << (base + 3);
      }
    }
  } else {                                // int32 layout
    const uint4* p = (const uint4*)((const u32*)adj + (size_t)row * 8192 + w * 32);
#pragma unroll
    for (int i = 0; i < 8; ++i) {
      const uint4 q = p[i];
      res |= (q.x ? 1u : 0u) << (i * 4 + 0);
      res |= (q.y ? 1u : 0u) << (i * 4 + 1);
      res |= (q.z ? 1u : 0u) << (i * 4 + 2);
      res |= (q.w ? 1u : 0u) << (i * 4 + 3);
    }
  }
  adjb[(size_t)row * 256 + w] = res;
}

// ---------------- column mean of x ----------------
__global__ void k_colsum(const float* __restrict__ x, float* __restrict__ part) {
  const int c = threadIdx.x;   // 512
  const int b = blockIdx.x;    // 64
  const int r0 = b * 128;
  float s = 0.f;
  for (int r = 0; r < 128; ++r) s += x[(size_t)(r0 + r) * 512 + c];
  part[b * 512 + c] = s;
}

__global__ void k_colsum2(const float* __restrict__ part, float* __restrict__ xbar) {
  const int c = threadIdx.x;
  float s = 0.f;
  for (int b = 0; b < 64; ++b) s += part[b * 512 + c];
  xbar[c] = s * (1.0f / 8192.0f);
}

// ---------------- gK = xbar@Wgk ; gV = xbar@Wgv + bgv ----------------
__global__ void k_gproj(const float* __restrict__ xbar, const float* __restrict__ Wgk,
                        const float* __restrict__ Wgv, const float* __restrict__ bgv,
                        float* __restrict__ gK, float* __restrict__ gV) {
  const int o = threadIdx.x;   // 512
  if (blockIdx.x == 0) {
    float s = 0.f;
    for (int k = 0; k < 512; ++k) s += xbar[k] * Wgk[(size_t)k * 512 + o];
    gK[o] = s;
  } else {
    float s = bgv[o];
    for (int k = 0; k < 512; ++k) s += xbar[k] * Wgv[(size_t)k * 512 + o];
    gV[o] = s;
  }
}

// ---------------- wcomb[k] = sum_o Wgq[k][o] * gK[o] ----------------
__global__ void k_wcomb(const float* __restrict__ Wgq, const float* __restrict__ gK,
                        float* __restrict__ wcomb) {
  const int w = threadIdx.x >> 6, l = threadIdx.x & 63;
  const int k = blockIdx.x * 4 + w;     // grid 128
  float s = 0.f;
  for (int o = l; o < 512; o += 64) s += Wgq[(size_t)k * 512 + o] * gK[o];
#pragma unroll
  for (int m = 1; m <= 32; m <<= 1) s += __shfl_xor(s, m);
  if (l == 0) wcomb[k] = s;
}

// ---------------- es[r] = mx[r].Wes ; gsc[r] = (mx[r].wcomb)*scale ----------------
__global__ void k_esgsc(const float* __restrict__ mx, const float* __restrict__ Wes,
                        const float* __restrict__ wcomb, float* __restrict__ es,
                        float* __restrict__ gsc) {
  const int w = threadIdx.x >> 6, l = threadIdx.x & 63;
  const int row = blockIdx.x * 4 + w;   // grid 2048
  float se = 0.f, sg = 0.f;
  for (int k = l; k < 512; k += 64) {
    const float v = mx[(size_t)row * 512 + k];
    se += v * Wes[k];
    sg += v * wcomb[k];
  }
#pragma unroll
  for (int m = 1; m <= 32; m <<= 1) { se += __shfl_xor(se, m); sg += __shfl_xor(sg, m); }
  if (l == 0) { es[row] = se; gsc[row] = sg * SCALE; }
}

// ------- bf16 GEMM x2 jobs: C[M x 1024] = A[M x 512] @ BT[1024 x 512]^T -------
struct GemmOuts { u16* obf[2]; float* of32[2]; const float* bias[2]; };

__global__ __launch_bounds__(256) void k_gemm(const u16* __restrict__ A0,
                                              const u16* __restrict__ BT0, GemmOuts o0j,
                                              const u16* __restrict__ A1,
                                              const u16* __restrict__ BT1, GemmOuts o1j) {
  __shared__ char lds[16384];
  char* ldsA = lds;
  char* ldsB = lds + 8192;
  const int job = blockIdx.y >> 3;
  const u16* A = job ? A1 : A0;
  const u16* BT = job ? BT1 : BT0;
  GemmOuts outs = job ? o1j : o0j;
  const int tid = threadIdx.x;
  const int w = tid >> 6, l = tid & 63, g = l >> 4, ln = l & 15;
  const int wr = w >> 1, wc = w & 1;
  const int bm0 = blockIdx.x * 128, bn0 = (blockIdx.y & 7) * 128;
  f32x4 acc[4][4] = {};
  for (int kt = 0; kt < 16; ++kt) {
    const int k0 = kt * 32;
    __syncthreads();
#pragma unroll
    for (int it = 0; it < 2; ++it) {
      const int i = it * 256 + tid;
      const int o = i * 16;
      const int row = o >> 6;
      const int pos = (o ^ (((o >> 7) & 3) << 4)) & 63;
      const int ldso = (it * 256 + w * 64) * 16;
      gl_lds16((const char*)A + ((size_t)(bm0 + row) * 512 + k0) * 2 + pos, ldsA + ldso);
      gl_lds16((const char*)BT + ((size_t)(bn0 + row) * 512 + k0) * 2 + pos, ldsB + ldso);
    }
    __syncthreads();
    bf16x8 a[4], b[4];
#pragma unroll
    for (int i = 0; i < 4; ++i) {
      const int r = wr * 64 + i * 16 + ln;
      int off = r * 64 + g * 16; off ^= ((r >> 1) & 3) << 4;
      a[i] = *(const bf16x8*)(ldsA + off);
    }
#pragma unroll
    for (int j = 0; j < 4; ++j) {
      const int r = wc * 64 + j * 16 + ln;
      int off = r * 64 + g * 16; off ^= ((r >> 1) & 3) << 4;
      b[j] = *(const bf16x8*)(ldsB + off);
    }
#pragma unroll
    for (int i = 0; i < 4; ++i)
#pragma unroll
      for (int j = 0; j < 4; ++j)
        acc[i][j] = __builtin_amdgcn_mfma_f32_16x16x32_bf16(a[i], b[j], acc[i][j], 0, 0, 0);
  }
#pragma unroll
  for (int j = 0; j < 4; ++j) {
    const int gcol = bn0 + wc * 64 + j * 16 + ln;
    const int seg = gcol >> 9, c = gcol & 511;
    const float bias = outs.bias[seg] ? outs.bias[seg][c] : 0.f;
#pragma unroll
    for (int i = 0; i < 4; ++i) {
#pragma unroll
      for (int r = 0; r < 4; ++r) {
        const int grow = bm0 + wr * 64 + i * 16 + g * 4 + r;
        const float v = acc[i][j][r] + bias;
        if (outs.of32[seg]) outs.of32[seg][(size_t)grow * 512 + c] = v;
        else                outs.obf[seg][(size_t)grow * 512 + c] = f2bf(v);
      }
    }
  }
}

// ---------------- lV [8192x512] -> lVT [512x8192] ----------------
__global__ void k_vtrans(const u16* __restrict__ lV, u16* __restrict__ lVT) {
  __shared__ u16 tile[32][33];
  const int c0 = blockIdx.x * 32;   // d
  const int r0 = blockIdx.y * 32;   // row
  const int tx = threadIdx.x, ty = threadIdx.y;  // (32,8)
#pragma unroll
  for (int yy = 0; yy < 4; ++yy)
    tile[ty + yy * 8][tx] = lV[(size_t)(r0 + ty + yy * 8) * 512 + (c0 + tx)];
  __syncthreads();
#pragma unroll
  for (int yy = 0; yy < 4; ++yy)
    lVT[(size_t)(c0 + ty + yy * 8) * 8192 + (r0 + tx)] = tile[tx][ty + yy * 8];
}

// ---- flash attention: full-d waves, streamed Q, 64 q-rows/block, 2 blocks/CU ----
__global__ __launch_bounds__(256, 2) void k_attn(
    const u16* __restrict__ lQ, const u16* __restrict__ lK, const u16* __restrict__ lVT,
    const u32* __restrict__ adjb, u16* __restrict__ Opart,
    float* __restrict__ mpart, float* __restrict__ lpart) {
  __shared__ char lds[69632];       // 32KB K + 32KB VT + 4KB P  (2 blocks/CU)
  char* ldsK = lds;
  char* ldsVT = lds + 32768;
  const int tid = threadIdx.x;
  const int w = tid >> 6, l = tid & 63, g = l >> 4, ln = l & 15;
  char* ldsP = lds + 65536 + w * 1024;            // per-wave slot
  const int bid = blockIdx.x;                     // grid 512
  const int split = (bid & 7) >> 1;               // XCD-pair affinity
  const int rblk = ((bid >> 3) << 1) | (bid & 1); // bijective 0..127
  const int rbase = rblk * 64 + w * 16;

  const u16* qptr = lQ + (size_t)(rbase + ln) * 512 + g * 8;  // this lane's Q stream

  f32x4 acc[32] = {};
  float rm = -3.0e38f, rl = 0.f;    // per-lane: running max/sum for q-row (rbase + ln)

  for (int ct = 0; ct < 64; ++ct) {
    const int c0 = split * 2048 + ct * 32;
    __syncthreads();                               // prev tile fully consumed
#pragma unroll
    for (int it = 0; it < 8; ++it) {               // stage K (pre-swizzled source)
      const int o = (it * 256 + tid) * 16;
      const int row = o >> 10;
      const int pos = (o ^ ((row & 7) << 4)) & 1023;
      gl_lds16((const char*)lK + (size_t)(c0 + row) * 1024 + pos,
               ldsK + (it * 256 + w * 64) * 16);
    }
#pragma unroll
    for (int it = 0; it < 8; ++it) {               // stage VT
      const int o = (it * 256 + tid) * 16;
      const int row = o >> 6;
      const int pos = (o ^ (((o >> 7) & 3) << 4)) & 63;
      gl_lds16((const char*)lVT + (size_t)row * 16384 + (size_t)c0 * 2 + pos,
               ldsVT + (it * 256 + w * 64) * 16);
    }
    __syncthreads();                               // staged (implicit vmcnt(0))

    const u32 wd = adjb[(size_t)(rbase + ln) * 256 + (c0 >> 5)];

    // ---- QK^T, swapped operands; Q streamed in two halves (L2-hot) ----
    f32x4 s0 = {}, s1 = {};
    bf16x8 qa[8];
#pragma unroll
    for (int h = 0; h < 2; ++h) {
#pragma unroll
      for (int kk = 0; kk < 8; ++kk)
        qa[kk] = *(const bf16x8*)(qptr + h * 256 + kk * 32);
      __builtin_amdgcn_s_setprio(1);
#pragma unroll
      for (int kk = 0; kk < 8; ++kk) {
        const int KK = h * 8 + kk;
        int off0 = ln * 1024 + KK * 64 + g * 16; off0 ^= (ln & 7) << 4;
        const bf16x8 kf0 = *(const bf16x8*)(ldsK + off0);
        s0 = __builtin_amdgcn_mfma_f32_16x16x32_bf16(kf0, qa[kk], s0, 0, 0, 0);
        const int rb = 16 + ln;
        int off1 = rb * 1024 + KK * 64 + g * 16; off1 ^= (rb & 7) << 4;
        const bf16x8 kf1 = *(const bf16x8*)(ldsK + off1);
        s1 = __builtin_amdgcn_mfma_f32_16x16x32_bf16(kf1, qa[kk], s1, 0, 0, 0);
      }
      __builtin_amdgcn_s_setprio(0);
    }

    // ---- softmax: lane owns q-row ln, kcols g*4+r (s0) and g*4+r+16 (s1) ----
    float p0[4], p1[4];
    float tm = -3.0e38f;
#pragma unroll
    for (int r = 0; r < 4; ++r) {
      const int kc = g * 4 + r;
      p0[r] = ((wd >> kc) & 1)        ? s0[r] * SCALE : -3.0e38f;
      p1[r] = ((wd >> (kc + 16)) & 1) ? s1[r] * SCALE : -3.0e38f;
      tm = fmaxf(tm, fmaxf(p0[r], p1[r]));
    }
    tm = fmaxf(tm, __shfl_xor(tm, 16));
    tm = fmaxf(tm, __shfl_xor(tm, 32));            // row max over all 32 kcols
    const float mn = fmaxf(rm, tm);
    const float f = __expf(rm - mn);               // ==1 when max unchanged
    float ps = 0.f;
#pragma unroll
    for (int r = 0; r < 4; ++r) {
      const int kc = g * 4 + r;
      p0[r] = ((wd >> kc) & 1)        ? __expf(p0[r] - mn) : 0.f;
      p1[r] = ((wd >> (kc + 16)) & 1) ? __expf(p1[r] - mn) : 0.f;
      ps += p0[r] + p1[r];
    }
    ps += __shfl_xor(ps, 16);
    ps += __shfl_xor(ps, 32);
    rl = rl * f + ps;
    rm = mn;

    if (__any(f < 1.0f)) {                         // exact skip: f==1 -> no-op
      f32x4 fv;
#pragma unroll
      for (int i = 0; i < 4; ++i) fv[i] = __shfl(f, g * 4 + i);
#pragma unroll
      for (int t = 0; t < 32; ++t) acc[t] *= fv;
    }

    // ---- P -> LDS (two b64 per lane, swizzled; same-wave read, no barrier) ----
    {
      const int sw = ((ln >> 1) & 3) << 4;
      ushort4 w0, w1;
      w0.x = f2bf(p0[0]); w0.y = f2bf(p0[1]); w0.z = f2bf(p0[2]); w0.w = f2bf(p0[3]);
      w1.x = f2bf(p1[0]); w1.y = f2bf(p1[1]); w1.z = f2bf(p1[2]); w1.w = f2bf(p1[3]);
      *(ushort4*)(ldsP + ((ln * 64 + g * 8) ^ sw))      = w0;
      *(ushort4*)(ldsP + ((ln * 64 + 32 + g * 8) ^ sw)) = w1;
    }
    const bf16x8 pa = *(const bf16x8*)(ldsP + ((ln * 64 + g * 16) ^ (((ln >> 1) & 3) << 4)));

    // ---- PV: full 512 dims ----
    __builtin_amdgcn_s_setprio(1);
#pragma unroll
    for (int t = 0; t < 32; ++t) {
      const int r = t * 16 + ln;
      int off = r * 64 + g * 16; off ^= ((r >> 1) & 3) << 4;
      const bf16x8 vf = *(const bf16x8*)(ldsVT + off);
      acc[t] = __builtin_amdgcn_mfma_f32_16x16x32_bf16(pa, vf, acc[t], 0, 0, 0);
    }
    __builtin_amdgcn_s_setprio(0);
  }

  // epilogue: store O (bf16); lanes 0..15 hold m/l for q-row rbase+l
#pragma unroll
  for (int t = 0; t < 32; ++t)
#pragma unroll
    for (int i = 0; i < 4; ++i)
      Opart[((size_t)split * 8192 + rbase + g * 4 + i) * 512 + t * 16 + ln] =
          f2bf(acc[t][i]);
  if (l < 16) {
    mpart[split * 8192 + rbase + l] = rm;
    lpart[split * 8192 + rbase + l] = rl;
  }
}

// ---------------- combine 4 splits + global/essential terms + final max ----------------
__global__ void k_combine(const u16* __restrict__ Opart, const float* __restrict__ mpart,
                          const float* __restrict__ lpart, const float* __restrict__ gsc,
                          const float* __restrict__ es, const float* __restrict__ gV,
                          const float* __restrict__ eV, const float* __restrict__ mx,
                          float* __restrict__ out) {
  const int row = blockIdx.x;
  const int tid = threadIdx.x;
  const float gs = gsc[row], e = es[row];
  float ms[4], ls[4];
  float M = fmaxf(gs, e);
#pragma unroll
  for (int s = 0; s < 4; ++s) {
    ms[s] = mpart[s * 8192 + row];
    ls[s] = lpart[s * 8192 + row];
    M = fmaxf(M, ms[s]);
  }
  float fs[4];
  const float eg = __expf(gs - M), ee = __expf(e - M);
  float denom = eg + ee;
#pragma unroll
  for (int s = 0; s < 4; ++s) { fs[s] = __expf(ms[s] - M); denom += ls[s] * fs[s]; }
  const float inv = 1.f / denom;
  for (int d = tid; d < 512; d += 256) {
    float o = eg * gV[d] + ee * eV[(size_t)row * 512 + d];
#pragma unroll
    for (int s = 0; s < 4; ++s)
      o += bf2f(Opart[((size_t)s * 8192 + row) * 512 + d]) * fs[s];
    out[(size_t)row * 512 + d] = fmaxf(o * inv, mx[(size_t)row * 512 + d]);
  }
}

// ---------------- workspace layout ----------------
static constexpr size_t OFF_XBF   = 0;
static constexpr size_t OFF_MXBF  = OFF_XBF   + (size_t)8192 * 512 * 2;
static constexpr size_t OFF_WMT   = OFF_MXBF  + (size_t)8192 * 512 * 2;
static constexpr size_t OFF_WXT   = OFF_WMT   + (size_t)1024 * 512 * 2;
static constexpr size_t OFF_LQ    = OFF_WXT   + (size_t)1024 * 512 * 2;
static constexpr size_t OFF_LK    = OFF_LQ    + (size_t)8192 * 512 * 2;
static constexpr size_t OFF_LV    = OFF_LK    + (size_t)8192 * 512 * 2;
static constexpr size_t OFF_LVT   = OFF_LV    + (size_t)8192 * 512 * 2;
static constexpr size_t OFF_EV    = OFF_LVT   + (size_t)8192 * 512 * 2;
static constexpr size_t OFF_ADJB  = OFF_EV    + (size_t)8192 * 512 * 4;
static constexpr size_t OFF_COLP  = OFF_ADJB  + (size_t)8192 * 256 * 4;
static constexpr size_t OFF_XBAR  = OFF_COLP  + (size_t)64 * 512 * 4;
static constexpr size_t OFF_GK    = OFF_XBAR  + 2048;
static constexpr size_t OFF_GV    = OFF_GK    + 2048;
static constexpr size_t OFF_WCOMB = OFF_GV    + 2048;
static constexpr size_t OFF_ES    = OFF_WCOMB + 2048;
static constexpr size_t OFF_GSC   = OFF_ES    + (size_t)8192 * 4;
static constexpr size_t OFF_OPART = OFF_GSC   + (size_t)8192 * 4;     // bf16, 4 splits
static constexpr size_t OFF_MPART = OFF_OPART + (size_t)4 * 8192 * 512 * 2;
static constexpr size_t OFF_LPART = OFF_MPART + (size_t)4 * 8192 * 4;
static constexpr size_t OFF_FLAG  = OFF_LPART + (size_t)4 * 8192 * 4;
static constexpr size_t WS_NEEDED = OFF_FLAG  + 64;

extern "C" void kernel_launch(void* const* d_in, const int* in_sizes, int n_in,
                              void* d_out, int out_size, void* d_ws, size_t ws_size,
                              hipStream_t stream) {
  const u8*    adj = (const u8*)d_in[0];
  const float* x   = (const float*)d_in[1];
  const float* mx  = (const float*)d_in[2];
  const float* Wlq = (const float*)d_in[3];
  const float* Wlk = (const float*)d_in[4];
  const float* Wlv = (const float*)d_in[5];
  const float* blv = (const float*)d_in[6];
  const float* Wgq = (const float*)d_in[7];
  const float* Wgk = (const float*)d_in[8];
  const float* Wgv = (const float*)d_in[9];
  const float* bgv = (const float*)d_in[10];
  const float* Wes = (const float*)d_in[11];
  const float* Wev = (const float*)d_in[12];
  const float* bev = (const float*)d_in[13];
  float* out = (float*)d_out;

  if (ws_size < WS_NEEDED) return;

  char* ws = (char*)d_ws;
  u16*   x_bf   = (u16*)(ws + OFF_XBF);
  u16*   mx_bf  = (u16*)(ws + OFF_MXBF);
  u16*   WmT    = (u16*)(ws + OFF_WMT);
  u16*   WxT    = (u16*)(ws + OFF_WXT);
  u16*   lQ     = (u16*)(ws + OFF_LQ);
  u16*   lK     = (u16*)(ws + OFF_LK);
  u16*   lV     = (u16*)(ws + OFF_LV);
  u16*   lVT    = (u16*)(ws + OFF_LVT);
  float* eV     = (float*)(ws + OFF_EV);
  u32*   adjb   = (u32*)(ws + OFF_ADJB);
  float* colp   = (float*)(ws + OFF_COLP);
  float* xbar   = (float*)(ws + OFF_XBAR);
  float* gK     = (float*)(ws + OFF_GK);
  float* gV     = (float*)(ws + OFF_GV);
  float* wcomb  = (float*)(ws + OFF_WCOMB);
  float* es     = (float*)(ws + OFF_ES);
  float* gsc    = (float*)(ws + OFF_GSC);
  u16*   Opart  = (u16*)(ws + OFF_OPART);
  float* mpart  = (float*)(ws + OFF_MPART);
  float* lpart  = (float*)(ws + OFF_LPART);
  u32*   flag   = (u32*)(ws + OFF_FLAG);

  hipMemsetAsync(flag, 0, 4, stream);
  k_adjdetect<<<1024, 256, 0, stream>>>(adj, flag);

  k_convert<<<2048, 256, 0, stream>>>(x, mx, x_bf, mx_bf);

  WtransJobs wj;
  wj.src[0] = Wlq; wj.dst[0] = WmT;
  wj.src[1] = Wev; wj.dst[1] = WmT + (size_t)512 * 512;
  wj.src[2] = Wlk; wj.dst[2] = WxT;
  wj.src[3] = Wlv; wj.dst[3] = WxT + (size_t)512 * 512;
  k_wtrans<<<dim3(16, 16, 4), dim3(32, 8), 0, stream>>>(wj);

  k_adjbits<<<8192, 256, 0, stream>>>(adj, flag, adjb);
  k_colsum<<<64, 512, 0, stream>>>(x, colp);
  k_colsum2<<<1, 512, 0, stream>>>(colp, xbar);
  k_gproj<<<2, 512, 0, stream>>>(xbar, Wgk, Wgv, bgv, gK, gV);
  k_wcomb<<<128, 256, 0, stream>>>(Wgq, gK, wcomb);
  k_esgsc<<<2048, 256, 0, stream>>>(mx, Wes, wcomb, es, gsc);

  GemmOuts o1;
  o1.obf[0] = lQ;      o1.of32[0] = nullptr; o1.bias[0] = nullptr;
  o1.obf[1] = nullptr; o1.of32[1] = eV;      o1.bias[1] = bev;
  GemmOuts o2;
  o2.obf[0] = lK; o2.of32[0] = nullptr; o2.bias[0] = nullptr;
  o2.obf[1] = lV; o2.of32[1] = nullptr; o2.bias[1] = blv;
  k_gemm<<<dim3(64, 16), 256, 0, stream>>>(mx_bf, WmT, o1, x_bf, WxT, o2);

  k_vtrans<<<dim3(16, 256), dim3(32, 8), 0, stream>>>(lV, lVT);
  k_attn<<<dim3(512), 256, 0, stream>>>(lQ, lK, lVT, adjb, Opart, mpart, lpart);
  k_combine<<<8192, 256, 0, stream>>>(Opart, mpart, lpart, gsc, es, gV, eV, mx, out);
}

// Round 15
// 492.553 us; speedup vs baseline: 3.1172x; 3.1172x over previous
//
#include <hip/hip_runtime.h>

typedef unsigned short u16;
typedef unsigned int   u32;
typedef unsigned char  u8;
typedef __attribute__((ext_vector_type(8))) short bf16x8;
typedef __attribute__((ext_vector_type(4))) float f32x4;

#define DEV __device__ __forceinline__

static constexpr float SCALE = 0.044194173824159216f; // 1/sqrt(512)

DEV u16 f2bf(float f) {
  u32 u = __float_as_uint(f);
  u32 r = (u + 0x7fffu + ((u >> 16) & 1u)) >> 16;
  return (u16)r;
}
DEV float bf2f(u16 v) { u32 u = (u32)v << 16; return __uint_as_float(u); }

DEV void gl_lds16(const void* g, void* l) {
  __builtin_amdgcn_global_load_lds(
      (__attribute__((address_space(1))) void*)(void*)g,
      (__attribute__((address_space(3))) void*)l, 16, 0, 0);
}

// ---------------- convert x, masked_x -> bf16 ----------------
__global__ void k_convert(const float* __restrict__ x, const float* __restrict__ mx,
                          u16* __restrict__ xbf, u16* __restrict__ mxbf) {
  const u32 stride = gridDim.x * blockDim.x;
  for (u32 idx = blockIdx.x * blockDim.x + threadIdx.x; idx < 2u * 1048576u; idx += stride) {
    const u32 t = idx >> 20;
    const u32 i = idx & 1048575u;
    const float4 v = t ? ((const float4*)mx)[i] : ((const float4*)x)[i];
    ushort4 o;
    o.x = f2bf(v.x); o.y = f2bf(v.y); o.z = f2bf(v.z); o.w = f2bf(v.w);
    ((ushort4*)(t ? mxbf : xbf))[i] = o;
  }
}

// ---------------- weight transpose (fp32 [k][o] -> bf16 [o][k]) ----------------
struct WtransJobs { const float* src[4]; u16* dst[4]; };

__global__ void k_wtrans(WtransJobs jobs) {
  __shared__ float tile[32][33];
  const int j  = blockIdx.z;
  const float* src = jobs.src[j];
  u16* dst = jobs.dst[j];
  const int o0 = blockIdx.x * 32;
  const int k0 = blockIdx.y * 32;
  const int tx = threadIdx.x, ty = threadIdx.y;   // (32,8)
#pragma unroll
  for (int yy = 0; yy < 4; ++yy)
    tile[ty + yy * 8][tx] = src[(size_t)(k0 + ty + yy * 8) * 512 + (o0 + tx)];
  __syncthreads();
#pragma unroll
  for (int yy = 0; yy < 4; ++yy)
    dst[(size_t)(o0 + ty + yy * 8) * 512 + (k0 + tx)] = f2bf(tile[tx][ty + yy * 8]);
}

// ---------------- adjacency layout detector ----------------
__global__ void k_adjdetect(const u8* __restrict__ adj, u32* __restrict__ flag) {
  u32 cnt = 0;
  const u32 stride = gridDim.x * blockDim.x;
  for (u32 i = blockIdx.x * blockDim.x + threadIdx.x; i < (1u << 22); i += stride)
    if ((i & 3u) && adj[i]) cnt++;
#pragma unroll
  for (int m = 1; m <= 32; m <<= 1) cnt += __shfl_xor(cnt, m);
  if ((threadIdx.x & 63) == 0 && cnt) atomicAdd(flag, cnt);
}

// ---------------- adjacency -> bitmask words (dual layout) ----------------
__global__ void k_adjbits(const u8* __restrict__ adj, const u32* __restrict__ flag,
                          u32* __restrict__ adjb) {
  const int row = blockIdx.x;
  const int w = threadIdx.x;              // 256 words per row
  u32 res = 0;
  if (*flag > 100u) {                     // byte layout
    const uint4* p = (const uint4*)(adj + (size_t)row * 8192 + w * 32);
#pragma unroll
    for (int i = 0; i < 2; ++i) {
      const uint4 q = p[i];
      const u32 vs[4] = {q.x, q.y, q.z, q.w};
#pragma unroll
      for (int jj = 0; jj < 4; ++jj) {
        const u32 v = vs[jj];
        const int base = i * 16 + jj * 4;
        res |= ((v & 0x000000FFu) ? 1u : 0u) << (base + 0);
        res |= ((v & 0x0000FF00u) ? 1u : 0u) << (base + 1);
        res |= ((v & 0x00FF0000u) ? 1u : 0u) << (base + 2);
        res |= ((v & 0xFF000000u) ? 1u : 0u) << (base + 3);
      }
    }
  } else {                                // int32 layout
    const uint4* p = (const uint4*)((const u32*)adj + (size_t)row * 8192 + w * 32);
#pragma unroll
    for (int i = 0; i < 8; ++i) {
      const uint4 q = p[i];
      res |= (q.x ? 1u : 0u) << (i * 4 + 0);
      res |= (q.y ? 1u : 0u) << (i * 4 + 1);
      res |= (q.z ? 1u : 0u) << (i * 4 + 2);
      res |= (q.w ? 1u : 0u) << (i * 4 + 3);
    }
  }
  adjb[(size_t)row * 256 + w] = res;
}

// ---------------- column mean of x ----------------
__global__ void k_colsum(const float* __restrict__ x, float* __restrict__ part) {
  const int c = threadIdx.x;   // 512
  const int b = blockIdx.x;    // 64
  const int r0 = b * 128;
  float s = 0.f;
  for (int r = 0; r < 128; ++r) s += x[(size_t)(r0 + r) * 512 + c];
  part[b * 512 + c] = s;
}

__global__ void k_colsum2(const float* __restrict__ part, float* __restrict__ xbar) {
  const int c = threadIdx.x;
  float s = 0.f;
  for (int b = 0; b < 64; ++b) s += part[b * 512 + c];
  xbar[c] = s * (1.0f / 8192.0f);
}

// ---------------- gK = xbar@Wgk ; gV = xbar@Wgv + bgv ----------------
__global__ void k_gproj(const float* __restrict__ xbar, const float* __restrict__ Wgk,
                        const float* __restrict__ Wgv, const float* __restrict__ bgv,
                        float* __restrict__ gK, float* __restrict__ gV) {
  const int o = threadIdx.x;   // 512
  if (blockIdx.x == 0) {
    float s = 0.f;
    for (int k = 0; k < 512; ++k) s += xbar[k] * Wgk[(size_t)k * 512 + o];
    gK[o] = s;
  } else {
    float s = bgv[o];
    for (int k = 0; k < 512; ++k) s += xbar[k] * Wgv[(size_t)k * 512 + o];
    gV[o] = s;
  }
}

// ---------------- wcomb[k] = sum_o Wgq[k][o] * gK[o] ----------------
__global__ void k_wcomb(const float* __restrict__ Wgq, const float* __restrict__ gK,
                        float* __restrict__ wcomb) {
  const int w = threadIdx.x >> 6, l = threadIdx.x & 63;
  const int k = blockIdx.x * 4 + w;     // grid 128
  float s = 0.f;
  for (int o = l; o < 512; o += 64) s += Wgq[(size_t)k * 512 + o] * gK[o];
#pragma unroll
  for (int m = 1; m <= 32; m <<= 1) s += __shfl_xor(s, m);
  if (l == 0) wcomb[k] = s;
}

// ---------------- es[r] = mx[r].Wes ; gsc[r] = (mx[r].wcomb)*scale ----------------
__global__ void k_esgsc(const float* __restrict__ mx, const float* __restrict__ Wes,
                        const float* __restrict__ wcomb, float* __restrict__ es,
                        float* __restrict__ gsc) {
  const int w = threadIdx.x >> 6, l = threadIdx.x & 63;
  const int row = blockIdx.x * 4 + w;   // grid 2048
  float se = 0.f, sg = 0.f;
  for (int k = l; k < 512; k += 64) {
    const float v = mx[(size_t)row * 512 + k];
    se += v * Wes[k];
    sg += v * wcomb[k];
  }
#pragma unroll
  for (int m = 1; m <= 32; m <<= 1) { se += __shfl_xor(se, m); sg += __shfl_xor(sg, m); }
  if (l == 0) { es[row] = se; gsc[row] = sg * SCALE; }
}

// ---------------- bf16 GEMM: C[M x 1024] = A[M x 512] @ BT[1024 x 512]^T ----------------
struct GemmOuts { u16* obf[2]; float* of32[2]; const float* bias[2]; };

__global__ __launch_bounds__(256) void k_gemm(const u16* __restrict__ A,
                                              const u16* __restrict__ BT, GemmOuts outs) {
  __shared__ char lds[16384];
  char* ldsA = lds;
  char* ldsB = lds + 8192;
  const int tid = threadIdx.x;
  const int w = tid >> 6, l = tid & 63, g = l >> 4, ln = l & 15;
  const int wr = w >> 1, wc = w & 1;
  const int bm0 = blockIdx.x * 128, bn0 = blockIdx.y * 128;
  f32x4 acc[4][4] = {};
  for (int kt = 0; kt < 16; ++kt) {
    const int k0 = kt * 32;
    __syncthreads();
#pragma unroll
    for (int it = 0; it < 2; ++it) {
      const int i = it * 256 + tid;
      const int o = i * 16;
      const int row = o >> 6;
      const int pos = (o ^ (((o >> 7) & 3) << 4)) & 63;
      const int ldso = (it * 256 + w * 64) * 16;
      gl_lds16((const char*)A + ((size_t)(bm0 + row) * 512 + k0) * 2 + pos, ldsA + ldso);
      gl_lds16((const char*)BT + ((size_t)(bn0 + row) * 512 + k0) * 2 + pos, ldsB + ldso);
    }
    __syncthreads();
    bf16x8 a[4], b[4];
#pragma unroll
    for (int i = 0; i < 4; ++i) {
      const int r = wr * 64 + i * 16 + ln;
      int off = r * 64 + g * 16; off ^= ((r >> 1) & 3) << 4;
      a[i] = *(const bf16x8*)(ldsA + off);
    }
#pragma unroll
    for (int j = 0; j < 4; ++j) {
      const int r = wc * 64 + j * 16 + ln;
      int off = r * 64 + g * 16; off ^= ((r >> 1) & 3) << 4;
      b[j] = *(const bf16x8*)(ldsB + off);
    }
#pragma unroll
    for (int i = 0; i < 4; ++i)
#pragma unroll
      for (int j = 0; j < 4; ++j)
        acc[i][j] = __builtin_amdgcn_mfma_f32_16x16x32_bf16(a[i], b[j], acc[i][j], 0, 0, 0);
  }
#pragma unroll
  for (int j = 0; j < 4; ++j) {
    const int gcol = bn0 + wc * 64 + j * 16 + ln;
    const int seg = gcol >> 9, c = gcol & 511;
    const float bias = outs.bias[seg] ? outs.bias[seg][c] : 0.f;
#pragma unroll
    for (int i = 0; i < 4; ++i) {
#pragma unroll
      for (int r = 0; r < 4; ++r) {
        const int grow = bm0 + wr * 64 + i * 16 + g * 4 + r;
        const float v = acc[i][j][r] + bias;
        if (outs.of32[seg]) outs.of32[seg][(size_t)grow * 512 + c] = v;
        else                outs.obf[seg][(size_t)grow * 512 + c] = f2bf(v);
      }
    }
  }
}

// ---------------- lV [8192x512] -> lVT [512x8192] ----------------
__global__ void k_vtrans(const u16* __restrict__ lV, u16* __restrict__ lVT) {
  __shared__ u16 tile[32][33];
  const int c0 = blockIdx.x * 32;   // d
  const int r0 = blockIdx.y * 32;   // row
  const int tx = threadIdx.x, ty = threadIdx.y;  // (32,8)
#pragma unroll
  for (int yy = 0; yy < 4; ++yy)
    tile[ty + yy * 8][tx] = lV[(size_t)(r0 + ty + yy * 8) * 512 + (c0 + tx)];
  __syncthreads();
#pragma unroll
  for (int yy = 0; yy < 4; ++yy)
    lVT[(size_t)(c0 + ty + yy * 8) * 8192 + (r0 + tx)] = tile[tx][ty + yy * 8];
}

// ---- flash attention: d-split with shared P (no redundant QK), 2 blocks/CU ----
__global__ __launch_bounds__(256, 2) void k_attn(
    const u16* __restrict__ lQ, const u16* __restrict__ lK, const u16* __restrict__ lVT,
    const u32* __restrict__ adjb, u16* __restrict__ Opart,
    float* __restrict__ mpart, float* __restrict__ lpart) {
  __shared__ char lds[69632];       // 32KB K + 32KB VT + 2KB P + 128B F
  char* ldsK = lds;
  char* ldsVT = lds + 32768;
  const int tid = threadIdx.x;
  const int w = tid >> 6, l = tid & 63, g = l >> 4, ln = l & 15;
  const int qg = w >> 1, dh = w & 1;              // 2 qgroups x 2 d-halves
  char* ldsP = lds + 65536 + qg * 1024;           // per-qgroup slot (shared by dh pair)
  float* ldsF = (float*)(lds + 67584);            // f per q-row [qg*16 + r]
  const int bid = blockIdx.x;                     // grid 1024
  const int split = (bid & 7) >> 1;               // XCD-pair affinity
  const int rblk = ((bid >> 3) << 1) | (bid & 1); // bijective 0..255
  const int rbase = rblk * 32 + qg * 16;

  bf16x8 q[16];
  if (dh == 0) {                    // only QK waves hold Q (wave-uniform branch)
#pragma unroll
    for (int kk = 0; kk < 16; ++kk)
      q[kk] = *(const bf16x8*)(lQ + (size_t)(rbase + ln) * 512 + kk * 32 + g * 8);
  }

  f32x4 acc[16] = {};
  float rm = -3.0e38f, rl = 0.f;    // maintained by dh==0 waves

  for (int ct = 0; ct < 64; ++ct) {
    const int c0 = split * 2048 + ct * 32;
    __syncthreads();                               // prev tile fully consumed
#pragma unroll
    for (int it = 0; it < 8; ++it) {               // stage K (pre-swizzled source)
      const int o = (it * 256 + tid) * 16;
      const int row = o >> 10;
      const int pos = (o ^ ((row & 7) << 4)) & 1023;
      gl_lds16((const char*)lK + (size_t)(c0 + row) * 1024 + pos,
               ldsK + (it * 256 + w * 64) * 16);
    }
#pragma unroll
    for (int it = 0; it < 8; ++it) {               // stage VT
      const int o = (it * 256 + tid) * 16;
      const int row = o >> 6;
      const int pos = (o ^ (((o >> 7) & 3) << 4)) & 63;
      gl_lds16((const char*)lVT + (size_t)row * 16384 + (size_t)c0 * 2 + pos,
               ldsVT + (it * 256 + w * 64) * 16);
    }
    __syncthreads();                               // staged (implicit vmcnt(0))

    if (dh == 0) {
      const u32 wd = adjb[(size_t)(rbase + ln) * 256 + (c0 >> 5)];

      // ---- QK^T, swapped operands: D[row=kcol grp][col=qrow=ln] ----
      f32x4 s0 = {}, s1 = {};
      __builtin_amdgcn_s_setprio(1);
#pragma unroll
      for (int kk = 0; kk < 16; ++kk) {
        int off0 = ln * 1024 + kk * 64 + g * 16; off0 ^= (ln & 7) << 4;
        const bf16x8 kf0 = *(const bf16x8*)(ldsK + off0);
        s0 = __builtin_amdgcn_mfma_f32_16x16x32_bf16(kf0, q[kk], s0, 0, 0, 0);
        const int rb = 16 + ln;
        int off1 = rb * 1024 + kk * 64 + g * 16; off1 ^= (rb & 7) << 4;
        const bf16x8 kf1 = *(const bf16x8*)(ldsK + off1);
        s1 = __builtin_amdgcn_mfma_f32_16x16x32_bf16(kf1, q[kk], s1, 0, 0, 0);
      }
      __builtin_amdgcn_s_setprio(0);

      // ---- softmax: lane owns q-row ln, kcols g*4+r (s0) and g*4+r+16 (s1) ----
      float p0[4], p1[4];
      float tm = -3.0e38f;
#pragma unroll
      for (int r = 0; r < 4; ++r) {
        const int kc = g * 4 + r;
        p0[r] = ((wd >> kc) & 1)        ? s0[r] * SCALE : -3.0e38f;
        p1[r] = ((wd >> (kc + 16)) & 1) ? s1[r] * SCALE : -3.0e38f;
        tm = fmaxf(tm, fmaxf(p0[r], p1[r]));
      }
      tm = fmaxf(tm, __shfl_xor(tm, 16));
      tm = fmaxf(tm, __shfl_xor(tm, 32));          // row max over all 32 kcols
      const float mn = fmaxf(rm, tm);
      const float f = __expf(rm - mn);             // ==1 when max unchanged
      float ps = 0.f;
#pragma unroll
      for (int r = 0; r < 4; ++r) {
        const int kc = g * 4 + r;
        p0[r] = ((wd >> kc) & 1)        ? __expf(p0[r] - mn) : 0.f;
        p1[r] = ((wd >> (kc + 16)) & 1) ? __expf(p1[r] - mn) : 0.f;
        ps += p0[r] + p1[r];
      }
      ps += __shfl_xor(ps, 16);
      ps += __shfl_xor(ps, 32);
      rl = rl * f + ps;
      rm = mn;

      // ---- publish P (swizzled bf16) + per-row rescale factor f ----
      {
        const int sw = ((ln >> 1) & 3) << 4;
        ushort4 w0, w1;
        w0.x = f2bf(p0[0]); w0.y = f2bf(p0[1]); w0.z = f2bf(p0[2]); w0.w = f2bf(p0[3]);
        w1.x = f2bf(p1[0]); w1.y = f2bf(p1[1]); w1.z = f2bf(p1[2]); w1.w = f2bf(p1[3]);
        *(ushort4*)(ldsP + ((ln * 64 + g * 8) ^ sw))      = w0;
        *(ushort4*)(ldsP + ((ln * 64 + 32 + g * 8) ^ sw)) = w1;
      }
      if (g == 0) ldsF[qg * 16 + ln] = f;          // f uniform across g for fixed ln
    }
    __syncthreads();                               // P + F visible to both dh waves

    // ---- rescale (factor from ldsF) + PV on this wave's 256-dim half ----
    f32x4 fv;
#pragma unroll
    for (int i = 0; i < 4; ++i) fv[i] = ldsF[qg * 16 + g * 4 + i];
    const bool anyf = (fv[0] < 1.f) | (fv[1] < 1.f) | (fv[2] < 1.f) | (fv[3] < 1.f);
    if (__any(anyf)) {
#pragma unroll
      for (int t = 0; t < 16; ++t) acc[t] *= fv;
    }
    const bf16x8 pa = *(const bf16x8*)(ldsP + ((ln * 64 + g * 16) ^ (((ln >> 1) & 3) << 4)));

    __builtin_amdgcn_s_setprio(1);
#pragma unroll
    for (int t = 0; t < 16; ++t) {
      const int r = (dh * 16 + t) * 16 + ln;
      int off = r * 64 + g * 16; off ^= ((r >> 1) & 3) << 4;
      const bf16x8 vf = *(const bf16x8*)(ldsVT + off);
      acc[t] = __builtin_amdgcn_mfma_f32_16x16x32_bf16(pa, vf, acc[t], 0, 0, 0);
    }
    __builtin_amdgcn_s_setprio(0);
  }

  // epilogue: store O (bf16, this wave's d-half); dh=0 lanes 0..15 store m/l
#pragma unroll
  for (int t = 0; t < 16; ++t)
#pragma unroll
    for (int i = 0; i < 4; ++i)
      Opart[((size_t)split * 8192 + rbase + g * 4 + i) * 512 + dh * 256 + t * 16 + ln] =
          f2bf(acc[t][i]);
  if (dh == 0 && l < 16) {
    mpart[split * 8192 + rbase + l] = rm;
    lpart[split * 8192 + rbase + l] = rl;
  }
}

// ---------------- combine 4 splits + global/essential terms + final max ----------------
__global__ void k_combine(const u16* __restrict__ Opart, const float* __restrict__ mpart,
                          const float* __restrict__ lpart, const float* __restrict__ gsc,
                          const float* __restrict__ es, const float* __restrict__ gV,
                          const float* __restrict__ eV, const float* __restrict__ mx,
                          float* __restrict__ out) {
  const int row = blockIdx.x;
  const int tid = threadIdx.x;
  const float gs = gsc[row], e = es[row];
  float ms[4], ls[4];
  float M = fmaxf(gs, e);
#pragma unroll
  for (int s = 0; s < 4; ++s) {
    ms[s] = mpart[s * 8192 + row];
    ls[s] = lpart[s * 8192 + row];
    M = fmaxf(M, ms[s]);
  }
  float fs[4];
  const float eg = __expf(gs - M), ee = __expf(e - M);
  float denom = eg + ee;
#pragma unroll
  for (int s = 0; s < 4; ++s) { fs[s] = __expf(ms[s] - M); denom += ls[s] * fs[s]; }
  const float inv = 1.f / denom;
  for (int d = tid; d < 512; d += 256) {
    float o = eg * gV[d] + ee * eV[(size_t)row * 512 + d];
#pragma unroll
    for (int s = 0; s < 4; ++s)
      o += bf2f(Opart[((size_t)s * 8192 + row) * 512 + d]) * fs[s];
    out[(size_t)row * 512 + d] = fmaxf(o * inv, mx[(size_t)row * 512 + d]);
  }
}

// ---------------- workspace layout ----------------
static constexpr size_t OFF_XBF   = 0;
static constexpr size_t OFF_MXBF  = OFF_XBF   + (size_t)8192 * 512 * 2;
static constexpr size_t OFF_WMT   = OFF_MXBF  + (size_t)8192 * 512 * 2;
static constexpr size_t OFF_WXT   = OFF_WMT   + (size_t)1024 * 512 * 2;
static constexpr size_t OFF_LQ    = OFF_WXT   + (size_t)1024 * 512 * 2;
static constexpr size_t OFF_LK    = OFF_LQ    + (size_t)8192 * 512 * 2;
static constexpr size_t OFF_LV    = OFF_LK    + (size_t)8192 * 512 * 2;
static constexpr size_t OFF_LVT   = OFF_LV    + (size_t)8192 * 512 * 2;
static constexpr size_t OFF_EV    = OFF_LVT   + (size_t)8192 * 512 * 2;
static constexpr size_t OFF_ADJB  = OFF_EV    + (size_t)8192 * 512 * 4;
static constexpr size_t OFF_COLP  = OFF_ADJB  + (size_t)8192 * 256 * 4;
static constexpr size_t OFF_XBAR  = OFF_COLP  + (size_t)64 * 512 * 4;
static constexpr size_t OFF_GK    = OFF_XBAR  + 2048;
static constexpr size_t OFF_GV    = OFF_GK    + 2048;
static constexpr size_t OFF_WCOMB = OFF_GV    + 2048;
static constexpr size_t OFF_ES    = OFF_WCOMB + 2048;
static constexpr size_t OFF_GSC   = OFF_ES    + (size_t)8192 * 4;
static constexpr size_t OFF_OPART = OFF_GSC   + (size_t)8192 * 4;     // bf16, 4 splits
static constexpr size_t OFF_MPART = OFF_OPART + (size_t)4 * 8192 * 512 * 2;
static constexpr size_t OFF_LPART = OFF_MPART + (size_t)4 * 8192 * 4;
static constexpr size_t OFF_FLAG  = OFF_LPART + (size_t)4 * 8192 * 4;
static constexpr size_t WS_NEEDED = OFF_FLAG  + 64;

extern "C" void kernel_launch(void* const* d_in, const int* in_sizes, int n_in,
                              void* d_out, int out_size, void* d_ws, size_t ws_size,
                              hipStream_t stream) {
  const u8*    adj = (const u8*)d_in[0];
  const float* x   = (const float*)d_in[1];
  const float* mx  = (const float*)d_in[2];
  const float* Wlq = (const float*)d_in[3];
  const float* Wlk = (const float*)d_in[4];
  const float* Wlv = (const float*)d_in[5];
  const float* blv = (const float*)d_in[6];
  const float* Wgq = (const float*)d_in[7];
  const float* Wgk = (const float*)d_in[8];
  const float* Wgv = (const float*)d_in[9];
  const float* bgv = (const float*)d_in[10];
  const float* Wes = (const float*)d_in[11];
  const float* Wev = (const float*)d_in[12];
  const float* bev = (const float*)d_in[13];
  float* out = (float*)d_out;

  if (ws_size < WS_NEEDED) return;

  char* ws = (char*)d_ws;
  u16*   x_bf   = (u16*)(ws + OFF_XBF);
  u16*   mx_bf  = (u16*)(ws + OFF_MXBF);
  u16*   WmT    = (u16*)(ws + OFF_WMT);
  u16*   WxT    = (u16*)(ws + OFF_WXT);
  u16*   lQ     = (u16*)(ws + OFF_LQ);
  u16*   lK     = (u16*)(ws + OFF_LK);
  u16*   lV     = (u16*)(ws + OFF_LV);
  u16*   lVT    = (u16*)(ws + OFF_LVT);
  float* eV     = (float*)(ws + OFF_EV);
  u32*   adjb   = (u32*)(ws + OFF_ADJB);
  float* colp   = (float*)(ws + OFF_COLP);
  float* xbar   = (float*)(ws + OFF_XBAR);
  float* gK     = (float*)(ws + OFF_GK);
  float* gV     = (float*)(ws + OFF_GV);
  float* wcomb  = (float*)(ws + OFF_WCOMB);
  float* es     = (float*)(ws + OFF_ES);
  float* gsc    = (float*)(ws + OFF_GSC);
  u16*   Opart  = (u16*)(ws + OFF_OPART);
  float* mpart  = (float*)(ws + OFF_MPART);
  float* lpart  = (float*)(ws + OFF_LPART);
  u32*   flag   = (u32*)(ws + OFF_FLAG);

  hipMemsetAsync(flag, 0, 4, stream);
  k_adjdetect<<<1024, 256, 0, stream>>>(adj, flag);

  k_convert<<<2048, 256, 0, stream>>>(x, mx, x_bf, mx_bf);

  WtransJobs wj;
  wj.src[0] = Wlq; wj.dst[0] = WmT;
  wj.src[1] = Wev; wj.dst[1] = WmT + (size_t)512 * 512;
  wj.src[2] = Wlk; wj.dst[2] = WxT;
  wj.src[3] = Wlv; wj.dst[3] = WxT + (size_t)512 * 512;
  k_wtrans<<<dim3(16, 16, 4), dim3(32, 8), 0, stream>>>(wj);

  k_adjbits<<<8192, 256, 0, stream>>>(adj, flag, adjb);
  k_colsum<<<64, 512, 0, stream>>>(x, colp);
  k_colsum2<<<1, 512, 0, stream>>>(colp, xbar);
  k_gproj<<<2, 512, 0, stream>>>(xbar, Wgk, Wgv, bgv, gK, gV);
  k_wcomb<<<128, 256, 0, stream>>>(Wgq, gK, wcomb);
  k_esgsc<<<2048, 256, 0, stream>>>(mx, Wes, wcomb, es, gsc);

  GemmOuts o1;
  o1.obf[0] = lQ;      o1.of32[0] = nullptr; o1.bias[0] = nullptr;
  o1.obf[1] = nullptr; o1.of32[1] = eV;      o1.bias[1] = bev;
  k_gemm<<<dim3(64, 8), 256, 0, stream>>>(mx_bf, WmT, o1);

  GemmOuts o2;
  o2.obf[0] = lK; o2.of32[0] = nullptr; o2.bias[0] = nullptr;
  o2.obf[1] = lV; o2.of32[1] = nullptr; o2.bias[1] = blv;
  k_gemm<<<dim3(64, 8), 256, 0, stream>>>(x_bf, WxT, o2);

  k_vtrans<<<dim3(16, 256), dim3(32, 8), 0, stream>>>(lV, lVT);
  k_attn<<<dim3(1024), 256, 0, stream>>>(lQ, lK, lVT, adjb, Opart, mpart, lpart);
  k_combine<<<8192, 256, 0, stream>>>(Opart, mpart, lpart, gsc, es, gV, eV, mx, out);
}

// Round 16
// 459.879 us; speedup vs baseline: 3.3387x; 1.0710x over previous
//
#include <hip/hip_runtime.h>

typedef unsigned short u16;
typedef unsigned int   u32;
typedef unsigned char  u8;
typedef __attribute__((ext_vector_type(8))) short bf16x8;
typedef __attribute__((ext_vector_type(4))) float f32x4;

#define DEV __device__ __forceinline__

static constexpr float SCALE = 0.044194173824159216f; // 1/sqrt(512)
static constexpr float MFIX  = 8.0f;                  // fixed softmax reference max

DEV u16 f2bf(float f) {
  u32 u = __float_as_uint(f);
  u32 r = (u + 0x7fffu + ((u >> 16) & 1u)) >> 16;
  return (u16)r;
}
DEV float bf2f(u16 v) { u32 u = (u32)v << 16; return __uint_as_float(u); }

DEV void gl_lds16(const void* g, void* l) {
  __builtin_amdgcn_global_load_lds(
      (__attribute__((address_space(1))) void*)(void*)g,
      (__attribute__((address_space(3))) void*)l, 16, 0, 0);
}

// ---------------- convert x, masked_x -> bf16 ----------------
__global__ void k_convert(const float* __restrict__ x, const float* __restrict__ mx,
                          u16* __restrict__ xbf, u16* __restrict__ mxbf) {
  const u32 stride = gridDim.x * blockDim.x;
  for (u32 idx = blockIdx.x * blockDim.x + threadIdx.x; idx < 2u * 1048576u; idx += stride) {
    const u32 t = idx >> 20;
    const u32 i = idx & 1048575u;
    const float4 v = t ? ((const float4*)mx)[i] : ((const float4*)x)[i];
    ushort4 o;
    o.x = f2bf(v.x); o.y = f2bf(v.y); o.z = f2bf(v.z); o.w = f2bf(v.w);
    ((ushort4*)(t ? mxbf : xbf))[i] = o;
  }
}

// ---------------- weight transpose (fp32 [k][o] -> bf16 [o][k]) ----------------
struct WtransJobs { const float* src[4]; u16* dst[4]; };

__global__ void k_wtrans(WtransJobs jobs) {
  __shared__ float tile[32][33];
  const int j  = blockIdx.z;
  const float* src = jobs.src[j];
  u16* dst = jobs.dst[j];
  const int o0 = blockIdx.x * 32;
  const int k0 = blockIdx.y * 32;
  const int tx = threadIdx.x, ty = threadIdx.y;   // (32,8)
#pragma unroll
  for (int yy = 0; yy < 4; ++yy)
    tile[ty + yy * 8][tx] = src[(size_t)(k0 + ty + yy * 8) * 512 + (o0 + tx)];
  __syncthreads();
#pragma unroll
  for (int yy = 0; yy < 4; ++yy)
    dst[(size_t)(o0 + ty + yy * 8) * 512 + (k0 + tx)] = f2bf(tile[tx][ty + yy * 8]);
}

// ---------------- adjacency layout detector ----------------
__global__ void k_adjdetect(const u8* __restrict__ adj, u32* __restrict__ flag) {
  u32 cnt = 0;
  const u32 stride = gridDim.x * blockDim.x;
  for (u32 i = blockIdx.x * blockDim.x + threadIdx.x; i < (1u << 22); i += stride)
    if ((i & 3u) && adj[i]) cnt++;
#pragma unroll
  for (int m = 1; m <= 32; m <<= 1) cnt += __shfl_xor(cnt, m);
  if ((threadIdx.x & 63) == 0 && cnt) atomicAdd(flag, cnt);
}

// ---------------- adjacency -> bitmask words (dual layout) ----------------
__global__ void k_adjbits(const u8* __restrict__ adj, const u32* __restrict__ flag,
                          u32* __restrict__ adjb) {
  const int row = blockIdx.x;
  const int w = threadIdx.x;              // 256 words per row
  u32 res = 0;
  if (*flag > 100u) {                     // byte layout
    const uint4* p = (const uint4*)(adj + (size_t)row * 8192 + w * 32);
#pragma unroll
    for (int i = 0; i < 2; ++i) {
      const uint4 q = p[i];
      const u32 vs[4] = {q.x, q.y, q.z, q.w};
#pragma unroll
      for (int jj = 0; jj < 4; ++jj) {
        const u32 v = vs[jj];
        const int base = i * 16 + jj * 4;
        res |= ((v & 0x000000FFu) ? 1u : 0u) << (base + 0);
        res |= ((v & 0x0000FF00u) ? 1u : 0u) << (base + 1);
        res |= ((v & 0x00FF0000u) ? 1u : 0u) << (base + 2);
        res |= ((v & 0xFF000000u) ? 1u : 0u) << (base + 3);
      }
    }
  } else {                                // int32 layout
    const uint4* p = (const uint4*)((const u32*)adj + (size_t)row * 8192 + w * 32);
#pragma unroll
    for (int i = 0; i < 8; ++i) {
      const uint4 q = p[i];
      res |= (q.x ? 1u : 0u) << (i * 4 + 0);
      res |= (q.y ? 1u : 0u) << (i * 4 + 1);
      res |= (q.z ? 1u : 0u) << (i * 4 + 2);
      res |= (q.w ? 1u : 0u) << (i * 4 + 3);
    }
  }
  adjb[(size_t)row * 256 + w] = res;
}

// ---------------- column mean of x ----------------
__global__ void k_colsum(const float* __restrict__ x, float* __restrict__ part) {
  const int c = threadIdx.x;   // 512
  const int b = blockIdx.x;    // 64
  const int r0 = b * 128;
  float s = 0.f;
  for (int r = 0; r < 128; ++r) s += x[(size_t)(r0 + r) * 512 + c];
  part[b * 512 + c] = s;
}

__global__ void k_colsum2(const float* __restrict__ part, float* __restrict__ xbar) {
  const int c = threadIdx.x;
  float s = 0.f;
  for (int b = 0; b < 64; ++b) s += part[b * 512 + c];
  xbar[c] = s * (1.0f / 8192.0f);
}

// ---------------- gK = xbar@Wgk ; gV = xbar@Wgv + bgv ----------------
__global__ void k_gproj(const float* __restrict__ xbar, const float* __restrict__ Wgk,
                        const float* __restrict__ Wgv, const float* __restrict__ bgv,
                        float* __restrict__ gK, float* __restrict__ gV) {
  const int o = threadIdx.x;   // 512
  if (blockIdx.x == 0) {
    float s = 0.f;
    for (int k = 0; k < 512; ++k) s += xbar[k] * Wgk[(size_t)k * 512 + o];
    gK[o] = s;
  } else {
    float s = bgv[o];
    for (int k = 0; k < 512; ++k) s += xbar[k] * Wgv[(size_t)k * 512 + o];
    gV[o] = s;
  }
}

// ---------------- wcomb[k] = sum_o Wgq[k][o] * gK[o] ----------------
__global__ void k_wcomb(const float* __restrict__ Wgq, const float* __restrict__ gK,
                        float* __restrict__ wcomb) {
  const int w = threadIdx.x >> 6, l = threadIdx.x & 63;
  const int k = blockIdx.x * 4 + w;     // grid 128
  float s = 0.f;
  for (int o = l; o < 512; o += 64) s += Wgq[(size_t)k * 512 + o] * gK[o];
#pragma unroll
  for (int m = 1; m <= 32; m <<= 1) s += __shfl_xor(s, m);
  if (l == 0) wcomb[k] = s;
}

// ---------------- es[r] = mx[r].Wes ; gsc[r] = (mx[r].wcomb)*scale ----------------
__global__ void k_esgsc(const float* __restrict__ mx, const float* __restrict__ Wes,
                        const float* __restrict__ wcomb, float* __restrict__ es,
                        float* __restrict__ gsc) {
  const int w = threadIdx.x >> 6, l = threadIdx.x & 63;
  const int row = blockIdx.x * 4 + w;   // grid 2048
  float se = 0.f, sg = 0.f;
  for (int k = l; k < 512; k += 64) {
    const float v = mx[(size_t)row * 512 + k];
    se += v * Wes[k];
    sg += v * wcomb[k];
  }
#pragma unroll
  for (int m = 1; m <= 32; m <<= 1) { se += __shfl_xor(se, m); sg += __shfl_xor(sg, m); }
  if (l == 0) { es[row] = se; gsc[row] = sg * SCALE; }
}

// ---------------- bf16 GEMM: C[M x 1024] = A[M x 512] @ BT[1024 x 512]^T ----------------
struct GemmOuts { u16* obf[2]; float* of32[2]; const float* bias[2]; };

__global__ __launch_bounds__(256) void k_gemm(const u16* __restrict__ A,
                                              const u16* __restrict__ BT, GemmOuts outs) {
  __shared__ char lds[16384];
  char* ldsA = lds;
  char* ldsB = lds + 8192;
  const int tid = threadIdx.x;
  const int w = tid >> 6, l = tid & 63, g = l >> 4, ln = l & 15;
  const int wr = w >> 1, wc = w & 1;
  const int bm0 = blockIdx.x * 128, bn0 = blockIdx.y * 128;
  f32x4 acc[4][4] = {};
  for (int kt = 0; kt < 16; ++kt) {
    const int k0 = kt * 32;
    __syncthreads();
#pragma unroll
    for (int it = 0; it < 2; ++it) {
      const int i = it * 256 + tid;
      const int o = i * 16;
      const int row = o >> 6;
      const int pos = (o ^ (((o >> 7) & 3) << 4)) & 63;
      const int ldso = (it * 256 + w * 64) * 16;
      gl_lds16((const char*)A + ((size_t)(bm0 + row) * 512 + k0) * 2 + pos, ldsA + ldso);
      gl_lds16((const char*)BT + ((size_t)(bn0 + row) * 512 + k0) * 2 + pos, ldsB + ldso);
    }
    __syncthreads();
    bf16x8 a[4], b[4];
#pragma unroll
    for (int i = 0; i < 4; ++i) {
      const int r = wr * 64 + i * 16 + ln;
      int off = r * 64 + g * 16; off ^= ((r >> 1) & 3) << 4;
      a[i] = *(const bf16x8*)(ldsA + off);
    }
#pragma unroll
    for (int j = 0; j < 4; ++j) {
      const int r = wc * 64 + j * 16 + ln;
      int off = r * 64 + g * 16; off ^= ((r >> 1) & 3) << 4;
      b[j] = *(const bf16x8*)(ldsB + off);
    }
#pragma unroll
    for (int i = 0; i < 4; ++i)
#pragma unroll
      for (int j = 0; j < 4; ++j)
        acc[i][j] = __builtin_amdgcn_mfma_f32_16x16x32_bf16(a[i], b[j], acc[i][j], 0, 0, 0);
  }
#pragma unroll
  for (int j = 0; j < 4; ++j) {
    const int gcol = bn0 + wc * 64 + j * 16 + ln;
    const int seg = gcol >> 9, c = gcol & 511;
    const float bias = outs.bias[seg] ? outs.bias[seg][c] : 0.f;
#pragma unroll
    for (int i = 0; i < 4; ++i) {
#pragma unroll
      for (int r = 0; r < 4; ++r) {
        const int grow = bm0 + wr * 64 + i * 16 + g * 4 + r;
        const float v = acc[i][j][r] + bias;
        if (outs.of32[seg]) outs.of32[seg][(size_t)grow * 512 + c] = v;
        else                outs.obf[seg][(size_t)grow * 512 + c] = f2bf(v);
      }
    }
  }
}

// ---------------- lV [8192x512] -> lVT [512x8192] ----------------
__global__ void k_vtrans(const u16* __restrict__ lV, u16* __restrict__ lVT) {
  __shared__ u16 tile[32][33];
  const int c0 = blockIdx.x * 32;   // d
  const int r0 = blockIdx.y * 32;   // row
  const int tx = threadIdx.x, ty = threadIdx.y;  // (32,8)
#pragma unroll
  for (int yy = 0; yy < 4; ++yy)
    tile[ty + yy * 8][tx] = lV[(size_t)(r0 + ty + yy * 8) * 512 + (c0 + tx)];
  __syncthreads();
#pragma unroll
  for (int yy = 0; yy < 4; ++yy)
    lVT[(size_t)(c0 + ty + yy * 8) * 8192 + (r0 + tx)] = tile[tx][ty + yy * 8];
}

// ---- flash attention: fixed-max softmax, shared P d-split, 2 blocks/CU ----
__global__ __launch_bounds__(256, 2) void k_attn(
    const u16* __restrict__ lQ, const u16* __restrict__ lK, const u16* __restrict__ lVT,
    const u32* __restrict__ adjb, u16* __restrict__ Opart, float* __restrict__ lpart) {
  __shared__ char lds[69632];       // 32KB K + 32KB VT + 2KB P
  char* ldsK = lds;
  char* ldsVT = lds + 32768;
  const int tid = threadIdx.x;
  const int w = tid >> 6, l = tid & 63, g = l >> 4, ln = l & 15;
  const int qg = w >> 1, dh = w & 1;              // 2 qgroups x 2 d-halves
  char* ldsP = lds + 65536 + qg * 1024;           // per-qgroup slot (shared by dh pair)
  const int bid = blockIdx.x;                     // grid 1024
  const int split = (bid & 7) >> 1;               // XCD-pair affinity
  const int rblk = ((bid >> 3) << 1) | (bid & 1); // bijective 0..255
  const int rbase = rblk * 32 + qg * 16;

  bf16x8 q[16];
  if (dh == 0) {                    // only QK waves hold Q (wave-uniform branch)
#pragma unroll
    for (int kk = 0; kk < 16; ++kk)
      q[kk] = *(const bf16x8*)(lQ + (size_t)(rbase + ln) * 512 + kk * 32 + g * 8);
  }

  f32x4 acc[16] = {};
  float rl = 0.f;                   // per-lane partial denom (dh==0 waves)

  for (int ct = 0; ct < 64; ++ct) {
    const int c0 = split * 2048 + ct * 32;
    __syncthreads();                               // prev tile fully consumed
#pragma unroll
    for (int it = 0; it < 8; ++it) {               // stage K (pre-swizzled source)
      const int o = (it * 256 + tid) * 16;
      const int row = o >> 10;
      const int pos = (o ^ ((row & 7) << 4)) & 1023;
      gl_lds16((const char*)lK + (size_t)(c0 + row) * 1024 + pos,
               ldsK + (it * 256 + w * 64) * 16);
    }
#pragma unroll
    for (int it = 0; it < 8; ++it) {               // stage VT
      const int o = (it * 256 + tid) * 16;
      const int row = o >> 6;
      const int pos = (o ^ (((o >> 7) & 3) << 4)) & 63;
      gl_lds16((const char*)lVT + (size_t)row * 16384 + (size_t)c0 * 2 + pos,
               ldsVT + (it * 256 + w * 64) * 16);
    }
    __syncthreads();                               // staged (implicit vmcnt(0))

    if (dh == 0) {
      const u32 wd = adjb[(size_t)(rbase + ln) * 256 + (c0 >> 5)];

      // ---- QK^T, swapped operands: D[row=kcol grp][col=qrow=ln] ----
      f32x4 s0 = {}, s1 = {};
      __builtin_amdgcn_s_setprio(1);
#pragma unroll
      for (int kk = 0; kk < 16; ++kk) {
        int off0 = ln * 1024 + kk * 64 + g * 16; off0 ^= (ln & 7) << 4;
        const bf16x8 kf0 = *(const bf16x8*)(ldsK + off0);
        s0 = __builtin_amdgcn_mfma_f32_16x16x32_bf16(kf0, q[kk], s0, 0, 0, 0);
        const int rb = 16 + ln;
        int off1 = rb * 1024 + kk * 64 + g * 16; off1 ^= (rb & 7) << 4;
        const bf16x8 kf1 = *(const bf16x8*)(ldsK + off1);
        s1 = __builtin_amdgcn_mfma_f32_16x16x32_bf16(kf1, q[kk], s1, 0, 0, 0);
      }
      __builtin_amdgcn_s_setprio(0);

      // ---- fixed-max softmax: p = adj ? exp(s*SCALE - MFIX) : 0 ----
      float p0[4], p1[4];
#pragma unroll
      for (int r = 0; r < 4; ++r) {
        const int kc = g * 4 + r;
        p0[r] = ((wd >> kc) & 1)        ? __expf(s0[r] * SCALE - MFIX) : 0.f;
        p1[r] = ((wd >> (kc + 16)) & 1) ? __expf(s1[r] * SCALE - MFIX) : 0.f;
        rl += p0[r] + p1[r];
      }

      // ---- publish P (swizzled bf16) ----
      {
        const int sw = ((ln >> 1) & 3) << 4;
        ushort4 w0, w1;
        w0.x = f2bf(p0[0]); w0.y = f2bf(p0[1]); w0.z = f2bf(p0[2]); w0.w = f2bf(p0[3]);
        w1.x = f2bf(p1[0]); w1.y = f2bf(p1[1]); w1.z = f2bf(p1[2]); w1.w = f2bf(p1[3]);
        *(ushort4*)(ldsP + ((ln * 64 + g * 8) ^ sw))      = w0;
        *(ushort4*)(ldsP + ((ln * 64 + 32 + g * 8) ^ sw)) = w1;
      }
    }
    __syncthreads();                               // P visible to both dh waves

    // ---- PV on this wave's 256-dim half ----
    const bf16x8 pa = *(const bf16x8*)(ldsP + ((ln * 64 + g * 16) ^ (((ln >> 1) & 3) << 4)));
    __builtin_amdgcn_s_setprio(1);
#pragma unroll
    for (int t = 0; t < 16; ++t) {
      const int r = (dh * 16 + t) * 16 + ln;
      int off = r * 64 + g * 16; off ^= ((r >> 1) & 3) << 4;
      const bf16x8 vf = *(const bf16x8*)(ldsVT + off);
      acc[t] = __builtin_amdgcn_mfma_f32_16x16x32_bf16(pa, vf, acc[t], 0, 0, 0);
    }
    __builtin_amdgcn_s_setprio(0);
  }

  // epilogue: store O (bf16, this wave's d-half); dh=0 reduces + stores denom
#pragma unroll
  for (int t = 0; t < 16; ++t)
#pragma unroll
    for (int i = 0; i < 4; ++i)
      Opart[((size_t)split * 8192 + rbase + g * 4 + i) * 512 + dh * 256 + t * 16 + ln] =
          f2bf(acc[t][i]);
  if (dh == 0) {
    rl += __shfl_xor(rl, 16);
    rl += __shfl_xor(rl, 32);                      // row-sum over all 32 kcols
    if (l < 16) lpart[split * 8192 + rbase + l] = rl;
  }
}

// ------- combine 4 splits (shared fixed max) + global/essential + final max -------
__global__ void k_combine(const u16* __restrict__ Opart, const float* __restrict__ lpart,
                          const float* __restrict__ gsc, const float* __restrict__ es,
                          const float* __restrict__ gV, const float* __restrict__ eV,
                          const float* __restrict__ mx, float* __restrict__ out) {
  const int row = blockIdx.x;
  const int tid = threadIdx.x;
  const float gs = gsc[row], e = es[row];
  const float M = fmaxf(MFIX, fmaxf(gs, e));
  const float eg = __expf(gs - M), ee = __expf(e - M);
  const float fL = __expf(MFIX - M);
  float lsum = 0.f;
#pragma unroll
  for (int s = 0; s < 4; ++s) lsum += lpart[s * 8192 + row];
  const float inv = 1.f / (eg + ee + fL * lsum);
  for (int d = tid; d < 512; d += 256) {
    float o = 0.f;
#pragma unroll
    for (int s = 0; s < 4; ++s)
      o += bf2f(Opart[((size_t)s * 8192 + row) * 512 + d]);
    o = o * fL + eg * gV[d] + ee * eV[(size_t)row * 512 + d];
    out[(size_t)row * 512 + d] = fmaxf(o * inv, mx[(size_t)row * 512 + d]);
  }
}

// ---------------- workspace layout ----------------
static constexpr size_t OFF_XBF   = 0;
static constexpr size_t OFF_MXBF  = OFF_XBF   + (size_t)8192 * 512 * 2;
static constexpr size_t OFF_WMT   = OFF_MXBF  + (size_t)8192 * 512 * 2;
static constexpr size_t OFF_WXT   = OFF_WMT   + (size_t)1024 * 512 * 2;
static constexpr size_t OFF_LQ    = OFF_WXT   + (size_t)1024 * 512 * 2;
static constexpr size_t OFF_LK    = OFF_LQ    + (size_t)8192 * 512 * 2;
static constexpr size_t OFF_LV    = OFF_LK    + (size_t)8192 * 512 * 2;
static constexpr size_t OFF_LVT   = OFF_LV    + (size_t)8192 * 512 * 2;
static constexpr size_t OFF_EV    = OFF_LVT   + (size_t)8192 * 512 * 2;
static constexpr size_t OFF_ADJB  = OFF_EV    + (size_t)8192 * 512 * 4;
static constexpr size_t OFF_COLP  = OFF_ADJB  + (size_t)8192 * 256 * 4;
static constexpr size_t OFF_XBAR  = OFF_COLP  + (size_t)64 * 512 * 4;
static constexpr size_t OFF_GK    = OFF_XBAR  + 2048;
static constexpr size_t OFF_GV    = OFF_GK    + 2048;
static constexpr size_t OFF_WCOMB = OFF_GV    + 2048;
static constexpr size_t OFF_ES    = OFF_WCOMB + 2048;
static constexpr size_t OFF_GSC   = OFF_ES    + (size_t)8192 * 4;
static constexpr size_t OFF_OPART = OFF_GSC   + (size_t)8192 * 4;     // bf16, 4 splits
static constexpr size_t OFF_LPART = OFF_OPART + (size_t)4 * 8192 * 512 * 2;
static constexpr size_t OFF_FLAG  = OFF_LPART + (size_t)4 * 8192 * 4;
static constexpr size_t WS_NEEDED = OFF_FLAG  + 64;

extern "C" void kernel_launch(void* const* d_in, const int* in_sizes, int n_in,
                              void* d_out, int out_size, void* d_ws, size_t ws_size,
                              hipStream_t stream) {
  const u8*    adj = (const u8*)d_in[0];
  const float* x   = (const float*)d_in[1];
  const float* mx  = (const float*)d_in[2];
  const float* Wlq = (const float*)d_in[3];
  const float* Wlk = (const float*)d_in[4];
  const float* Wlv = (const float*)d_in[5];
  const float* blv = (const float*)d_in[6];
  const float* Wgq = (const float*)d_in[7];
  const float* Wgk = (const float*)d_in[8];
  const float* Wgv = (const float*)d_in[9];
  const float* bgv = (const float*)d_in[10];
  const float* Wes = (const float*)d_in[11];
  const float* Wev = (const float*)d_in[12];
  const float* bev = (const float*)d_in[13];
  float* out = (float*)d_out;

  if (ws_size < WS_NEEDED) return;

  char* ws = (char*)d_ws;
  u16*   x_bf   = (u16*)(ws + OFF_XBF);
  u16*   mx_bf  = (u16*)(ws + OFF_MXBF);
  u16*   WmT    = (u16*)(ws + OFF_WMT);
  u16*   WxT    = (u16*)(ws + OFF_WXT);
  u16*   lQ     = (u16*)(ws + OFF_LQ);
  u16*   lK     = (u16*)(ws + OFF_LK);
  u16*   lV     = (u16*)(ws + OFF_LV);
  u16*   lVT    = (u16*)(ws + OFF_LVT);
  float* eV     = (float*)(ws + OFF_EV);
  u32*   adjb   = (u32*)(ws + OFF_ADJB);
  float* colp   = (float*)(ws + OFF_COLP);
  float* xbar   = (float*)(ws + OFF_XBAR);
  float* gK     = (float*)(ws + OFF_GK);
  float* gV     = (float*)(ws + OFF_GV);
  float* wcomb  = (float*)(ws + OFF_WCOMB);
  float* es     = (float*)(ws + OFF_ES);
  float* gsc    = (float*)(ws + OFF_GSC);
  u16*   Opart  = (u16*)(ws + OFF_OPART);
  float* lpart  = (float*)(ws + OFF_LPART);
  u32*   flag   = (u32*)(ws + OFF_FLAG);

  hipMemsetAsync(flag, 0, 4, stream);
  k_adjdetect<<<1024, 256, 0, stream>>>(adj, flag);

  k_convert<<<2048, 256, 0, stream>>>(x, mx, x_bf, mx_bf);

  WtransJobs wj;
  wj.src[0] = Wlq; wj.dst[0] = WmT;
  wj.src[1] = Wev; wj.dst[1] = WmT + (size_t)512 * 512;
  wj.src[2] = Wlk; wj.dst[2] = WxT;
  wj.src[3] = Wlv; wj.dst[3] = WxT + (size_t)512 * 512;
  k_wtrans<<<dim3(16, 16, 4), dim3(32, 8), 0, stream>>>(wj);

  k_adjbits<<<8192, 256, 0, stream>>>(adj, flag, adjb);
  k_colsum<<<64, 512, 0, stream>>>(x, colp);
  k_colsum2<<<1, 512, 0, stream>>>(colp, xbar);
  k_gproj<<<2, 512, 0, stream>>>(xbar, Wgk, Wgv, bgv, gK, gV);
  k_wcomb<<<128, 256, 0, stream>>>(Wgq, gK, wcomb);
  k_esgsc<<<2048, 256, 0, stream>>>(mx, Wes, wcomb, es, gsc);

  GemmOuts o1;
  o1.obf[0] = lQ;      o1.of32[0] = nullptr; o1.bias[0] = nullptr;
  o1.obf[1] = nullptr; o1.of32[1] = eV;      o1.bias[1] = bev;
  k_gemm<<<dim3(64, 8), 256, 0, stream>>>(mx_bf, WmT, o1);

  GemmOuts o2;
  o2.obf[0] = lK; o2.of32[0] = nullptr; o2.bias[0] = nullptr;
  o2.obf[1] = lV; o2.of32[1] = nullptr; o2.bias[1] = blv;
  k_gemm<<<dim3(64, 8), 256, 0, stream>>>(x_bf, WxT, o2);

  k_vtrans<<<dim3(16, 256), dim3(32, 8), 0, stream>>>(lV, lVT);
  k_attn<<<dim3(1024), 256, 0, stream>>>(lQ, lK, lVT, adjb, Opart, lpart);
  k_combine<<<8192, 256, 0, stream>>>(Opart, lpart, gsc, es, gV, eV, mx, out);
}

// Round 17
// 453.946 us; speedup vs baseline: 3.3823x; 1.0131x over previous
//
#include <hip/hip_runtime.h>

typedef unsigned short u16;
typedef unsigned int   u32;
typedef unsigned char  u8;
typedef __attribute__((ext_vector_type(8))) short bf16x8;
typedef __attribute__((ext_vector_type(4))) float f32x4;

#define DEV __device__ __forceinline__

static constexpr float SCALE = 0.044194173824159216f; // 1/sqrt(512)
static constexpr float MFIX  = 8.0f;                  // fixed softmax reference max

DEV u16 f2bf(float f) {
  u32 u = __float_as_uint(f);
  u32 r = (u + 0x7fffu + ((u >> 16) & 1u)) >> 16;
  return (u16)r;
}
DEV float bf2f(u16 v) { u32 u = (u32)v << 16; return __uint_as_float(u); }

DEV void gl_lds16(const void* g, void* l) {
  __builtin_amdgcn_global_load_lds(
      (__attribute__((address_space(1))) void*)(void*)g,
      (__attribute__((address_space(3))) void*)l, 16, 0, 0);
}

// ---------------- convert x, masked_x -> bf16 ----------------
__global__ void k_convert(const float* __restrict__ x, const float* __restrict__ mx,
                          u16* __restrict__ xbf, u16* __restrict__ mxbf) {
  const u32 stride = gridDim.x * blockDim.x;
  for (u32 idx = blockIdx.x * blockDim.x + threadIdx.x; idx < 2u * 1048576u; idx += stride) {
    const u32 t = idx >> 20;
    const u32 i = idx & 1048575u;
    const float4 v = t ? ((const float4*)mx)[i] : ((const float4*)x)[i];
    ushort4 o;
    o.x = f2bf(v.x); o.y = f2bf(v.y); o.z = f2bf(v.z); o.w = f2bf(v.w);
    ((ushort4*)(t ? mxbf : xbf))[i] = o;
  }
}

// ---------------- weight transpose (fp32 [k][o] -> bf16 [o][k]) ----------------
struct WtransJobs { const float* src[4]; u16* dst[4]; };

__global__ void k_wtrans(WtransJobs jobs) {
  __shared__ float tile[32][33];
  const int j  = blockIdx.z;
  const float* src = jobs.src[j];
  u16* dst = jobs.dst[j];
  const int o0 = blockIdx.x * 32;
  const int k0 = blockIdx.y * 32;
  const int tx = threadIdx.x, ty = threadIdx.y;   // (32,8)
#pragma unroll
  for (int yy = 0; yy < 4; ++yy)
    tile[ty + yy * 8][tx] = src[(size_t)(k0 + ty + yy * 8) * 512 + (o0 + tx)];
  __syncthreads();
#pragma unroll
  for (int yy = 0; yy < 4; ++yy)
    dst[(size_t)(o0 + ty + yy * 8) * 512 + (k0 + tx)] = f2bf(tile[tx][ty + yy * 8]);
}

// ---------------- adjacency layout detector ----------------
__global__ void k_adjdetect(const u8* __restrict__ adj, u32* __restrict__ flag) {
  u32 cnt = 0;
  const u32 stride = gridDim.x * blockDim.x;
  for (u32 i = blockIdx.x * blockDim.x + threadIdx.x; i < (1u << 22); i += stride)
    if ((i & 3u) && adj[i]) cnt++;
#pragma unroll
  for (int m = 1; m <= 32; m <<= 1) cnt += __shfl_xor(cnt, m);
  if ((threadIdx.x & 63) == 0 && cnt) atomicAdd(flag, cnt);
}

// ---------------- adjacency -> bitmask words (dual layout) ----------------
__global__ void k_adjbits(const u8* __restrict__ adj, const u32* __restrict__ flag,
                          u32* __restrict__ adjb) {
  const int row = blockIdx.x;
  const int w = threadIdx.x;              // 256 words per row
  u32 res = 0;
  if (*flag > 100u) {                     // byte layout
    const uint4* p = (const uint4*)(adj + (size_t)row * 8192 + w * 32);
#pragma unroll
    for (int i = 0; i < 2; ++i) {
      const uint4 q = p[i];
      const u32 vs[4] = {q.x, q.y, q.z, q.w};
#pragma unroll
      for (int jj = 0; jj < 4; ++jj) {
        const u32 v = vs[jj];
        const int base = i * 16 + jj * 4;
        res |= ((v & 0x000000FFu) ? 1u : 0u) << (base + 0);
        res |= ((v & 0x0000FF00u) ? 1u : 0u) << (base + 1);
        res |= ((v & 0x00FF0000u) ? 1u : 0u) << (base + 2);
        res |= ((v & 0xFF000000u) ? 1u : 0u) << (base + 3);
      }
    }
  } else {                                // int32 layout
    const uint4* p = (const uint4*)((const u32*)adj + (size_t)row * 8192 + w * 32);
#pragma unroll
    for (int i = 0; i < 8; ++i) {
      const uint4 q = p[i];
      res |= (q.x ? 1u : 0u) << (i * 4 + 0);
      res |= (q.y ? 1u : 0u) << (i * 4 + 1);
      res |= (q.z ? 1u : 0u) << (i * 4 + 2);
      res |= (q.w ? 1u : 0u) << (i * 4 + 3);
    }
  }
  adjb[(size_t)row * 256 + w] = res;
}

// ---------------- column mean of x ----------------
__global__ void k_colsum(const float* __restrict__ x, float* __restrict__ part) {
  const int c = threadIdx.x;   // 512
  const int b = blockIdx.x;    // 64
  const int r0 = b * 128;
  float s = 0.f;
  for (int r = 0; r < 128; ++r) s += x[(size_t)(r0 + r) * 512 + c];
  part[b * 512 + c] = s;
}

__global__ void k_colsum2(const float* __restrict__ part, float* __restrict__ xbar) {
  const int c = threadIdx.x;
  float s = 0.f;
  for (int b = 0; b < 64; ++b) s += part[b * 512 + c];
  xbar[c] = s * (1.0f / 8192.0f);
}

// ---------------- gK = xbar@Wgk ; gV = xbar@Wgv + bgv ----------------
__global__ void k_gproj(const float* __restrict__ xbar, const float* __restrict__ Wgk,
                        const float* __restrict__ Wgv, const float* __restrict__ bgv,
                        float* __restrict__ gK, float* __restrict__ gV) {
  const int o = threadIdx.x;   // 512
  if (blockIdx.x == 0) {
    float s = 0.f;
    for (int k = 0; k < 512; ++k) s += xbar[k] * Wgk[(size_t)k * 512 + o];
    gK[o] = s;
  } else {
    float s = bgv[o];
    for (int k = 0; k < 512; ++k) s += xbar[k] * Wgv[(size_t)k * 512 + o];
    gV[o] = s;
  }
}

// ---------------- wcomb[k] = sum_o Wgq[k][o] * gK[o] ----------------
__global__ void k_wcomb(const float* __restrict__ Wgq, const float* __restrict__ gK,
                        float* __restrict__ wcomb) {
  const int w = threadIdx.x >> 6, l = threadIdx.x & 63;
  const int k = blockIdx.x * 4 + w;     // grid 128
  float s = 0.f;
  for (int o = l; o < 512; o += 64) s += Wgq[(size_t)k * 512 + o] * gK[o];
#pragma unroll
  for (int m = 1; m <= 32; m <<= 1) s += __shfl_xor(s, m);
  if (l == 0) wcomb[k] = s;
}

// ---------------- es[r] = mx[r].Wes ; gsc[r] = (mx[r].wcomb)*scale ----------------
__global__ void k_esgsc(const float* __restrict__ mx, const float* __restrict__ Wes,
                        const float* __restrict__ wcomb, float* __restrict__ es,
                        float* __restrict__ gsc) {
  const int w = threadIdx.x >> 6, l = threadIdx.x & 63;
  const int row = blockIdx.x * 4 + w;   // grid 2048
  float se = 0.f, sg = 0.f;
  for (int k = l; k < 512; k += 64) {
    const float v = mx[(size_t)row * 512 + k];
    se += v * Wes[k];
    sg += v * wcomb[k];
  }
#pragma unroll
  for (int m = 1; m <= 32; m <<= 1) { se += __shfl_xor(se, m); sg += __shfl_xor(sg, m); }
  if (l == 0) { es[row] = se; gsc[row] = sg * SCALE; }
}

// ---------------- bf16 GEMM: C[M x 1024] = A[M x 512] @ BT[1024 x 512]^T ----------------
struct GemmOuts { u16* obf[2]; float* of32[2]; const float* bias[2]; };

__global__ __launch_bounds__(256) void k_gemm(const u16* __restrict__ A,
                                              const u16* __restrict__ BT, GemmOuts outs) {
  __shared__ char lds[16384];
  char* ldsA = lds;
  char* ldsB = lds + 8192;
  const int tid = threadIdx.x;
  const int w = tid >> 6, l = tid & 63, g = l >> 4, ln = l & 15;
  const int wr = w >> 1, wc = w & 1;
  const int bm0 = blockIdx.x * 128, bn0 = blockIdx.y * 128;
  f32x4 acc[4][4] = {};
  for (int kt = 0; kt < 16; ++kt) {
    const int k0 = kt * 32;
    __syncthreads();
#pragma unroll
    for (int it = 0; it < 2; ++it) {
      const int i = it * 256 + tid;
      const int o = i * 16;
      const int row = o >> 6;
      const int pos = (o ^ (((o >> 7) & 3) << 4)) & 63;
      const int ldso = (it * 256 + w * 64) * 16;
      gl_lds16((const char*)A + ((size_t)(bm0 + row) * 512 + k0) * 2 + pos, ldsA + ldso);
      gl_lds16((const char*)BT + ((size_t)(bn0 + row) * 512 + k0) * 2 + pos, ldsB + ldso);
    }
    __syncthreads();
    bf16x8 a[4], b[4];
#pragma unroll
    for (int i = 0; i < 4; ++i) {
      const int r = wr * 64 + i * 16 + ln;
      int off = r * 64 + g * 16; off ^= ((r >> 1) & 3) << 4;
      a[i] = *(const bf16x8*)(ldsA + off);
    }
#pragma unroll
    for (int j = 0; j < 4; ++j) {
      const int r = wc * 64 + j * 16 + ln;
      int off = r * 64 + g * 16; off ^= ((r >> 1) & 3) << 4;
      b[j] = *(const bf16x8*)(ldsB + off);
    }
#pragma unroll
    for (int i = 0; i < 4; ++i)
#pragma unroll
      for (int j = 0; j < 4; ++j)
        acc[i][j] = __builtin_amdgcn_mfma_f32_16x16x32_bf16(a[i], b[j], acc[i][j], 0, 0, 0);
  }
#pragma unroll
  for (int j = 0; j < 4; ++j) {
    const int gcol = bn0 + wc * 64 + j * 16 + ln;
    const int seg = gcol >> 9, c = gcol & 511;
    const float bias = outs.bias[seg] ? outs.bias[seg][c] : 0.f;
#pragma unroll
    for (int i = 0; i < 4; ++i) {
#pragma unroll
      for (int r = 0; r < 4; ++r) {
        const int grow = bm0 + wr * 64 + i * 16 + g * 4 + r;
        const float v = acc[i][j][r] + bias;
        if (outs.of32[seg]) outs.of32[seg][(size_t)grow * 512 + c] = v;
        else                outs.obf[seg][(size_t)grow * 512 + c] = f2bf(v);
      }
    }
  }
}

// ---------------- lV [8192x512] -> lVT [512x8192] ----------------
__global__ void k_vtrans(const u16* __restrict__ lV, u16* __restrict__ lVT) {
  __shared__ u16 tile[32][33];
  const int c0 = blockIdx.x * 32;   // d
  const int r0 = blockIdx.y * 32;   // row
  const int tx = threadIdx.x, ty = threadIdx.y;  // (32,8)
#pragma unroll
  for (int yy = 0; yy < 4; ++yy)
    tile[ty + yy * 8][tx] = lV[(size_t)(r0 + ty + yy * 8) * 512 + (c0 + tx)];
  __syncthreads();
#pragma unroll
  for (int yy = 0; yy < 4; ++yy)
    lVT[(size_t)(c0 + ty + yy * 8) * 8192 + (r0 + tx)] = tile[tx][ty + yy * 8];
}

// ---- flash attention: balanced kcol-split QK + d-split PV, 2 blocks/CU ----
__global__ __launch_bounds__(256, 2) void k_attn(
    const u16* __restrict__ lQ, const u16* __restrict__ lK, const u16* __restrict__ lVT,
    const u32* __restrict__ adjb, u16* __restrict__ Opart, float* __restrict__ lpart) {
  __shared__ char lds[69632];       // 32KB K + 32KB VT + 2KB P
  char* ldsK = lds;
  char* ldsVT = lds + 32768;
  const int tid = threadIdx.x;
  const int w = tid >> 6, l = tid & 63, g = l >> 4, ln = l & 15;
  const int qg = w >> 1, dh = w & 1;              // 2 qgroups x 2 (kcol-half / d-half)
  char* ldsP = lds + 65536 + qg * 1024;           // per-qgroup slot (shared by dh pair)
  const int bid = blockIdx.x;                     // grid 1024
  const int split = (bid & 7) >> 1;               // XCD-pair affinity
  const int rblk = ((bid >> 3) << 1) | (bid & 1); // bijective 0..255
  const int rbase = rblk * 32 + qg * 16;

  bf16x8 q[16];
#pragma unroll
  for (int kk = 0; kk < 16; ++kk)
    q[kk] = *(const bf16x8*)(lQ + (size_t)(rbase + ln) * 512 + kk * 32 + g * 8);

  f32x4 acc[16] = {};
  float rl = 0.f;                   // per-lane partial denom (this wave's 16 kcols)

  for (int ct = 0; ct < 64; ++ct) {
    const int c0 = split * 2048 + ct * 32;
    __syncthreads();                               // prev tile fully consumed
#pragma unroll
    for (int it = 0; it < 8; ++it) {               // stage K (pre-swizzled source)
      const int o = (it * 256 + tid) * 16;
      const int row = o >> 10;
      const int pos = (o ^ ((row & 7) << 4)) & 1023;
      gl_lds16((const char*)lK + (size_t)(c0 + row) * 1024 + pos,
               ldsK + (it * 256 + w * 64) * 16);
    }
#pragma unroll
    for (int it = 0; it < 8; ++it) {               // stage VT
      const int o = (it * 256 + tid) * 16;
      const int row = o >> 6;
      const int pos = (o ^ (((o >> 7) & 3) << 4)) & 63;
      gl_lds16((const char*)lVT + (size_t)row * 16384 + (size_t)c0 * 2 + pos,
               ldsVT + (it * 256 + w * 64) * 16);
    }
    __syncthreads();                               // staged (implicit vmcnt(0))

    const u32 wd = adjb[(size_t)(rbase + ln) * 256 + (c0 >> 5)];

    // ---- QK^T on this wave's 16 kcols (dh*16 .. dh*16+15), swapped operands ----
    f32x4 s = {};
    {
      const int ra = dh * 16 + ln;
      const int sw = (ra & 7) << 4;
      __builtin_amdgcn_s_setprio(1);
#pragma unroll
      for (int kk = 0; kk < 16; ++kk) {
        const int off = (ra * 1024 + kk * 64 + g * 16) ^ sw;
        const bf16x8 kf = *(const bf16x8*)(ldsK + off);
        s = __builtin_amdgcn_mfma_f32_16x16x32_bf16(kf, q[kk], s, 0, 0, 0);
      }
      __builtin_amdgcn_s_setprio(0);
    }

    // ---- fixed-max softmax on this wave's 4 kcols/lane ----
    float p[4];
#pragma unroll
    for (int r = 0; r < 4; ++r) {
      const int kc = dh * 16 + g * 4 + r;
      p[r] = ((wd >> kc) & 1) ? __expf(s[r] * SCALE - MFIX) : 0.f;
      rl += p[r];
    }

    // ---- publish this wave's P half (swizzled bf16) ----
    {
      const int sw = ((ln >> 1) & 3) << 4;
      ushort4 w0;
      w0.x = f2bf(p[0]); w0.y = f2bf(p[1]); w0.z = f2bf(p[2]); w0.w = f2bf(p[3]);
      *(ushort4*)(ldsP + ((ln * 64 + dh * 32 + g * 8) ^ sw)) = w0;
    }
    __syncthreads();                               // both P halves visible

    // ---- PV on this wave's 256-dim half ----
    const bf16x8 pa = *(const bf16x8*)(ldsP + ((ln * 64 + g * 16) ^ (((ln >> 1) & 3) << 4)));
    __builtin_amdgcn_s_setprio(1);
#pragma unroll
    for (int t = 0; t < 16; ++t) {
      const int r = (dh * 16 + t) * 16 + ln;
      int off = r * 64 + g * 16; off ^= ((r >> 1) & 3) << 4;
      const bf16x8 vf = *(const bf16x8*)(ldsVT + off);
      acc[t] = __builtin_amdgcn_mfma_f32_16x16x32_bf16(pa, vf, acc[t], 0, 0, 0);
    }
    __builtin_amdgcn_s_setprio(0);
  }

  // epilogue: store O (bf16, this wave's d-half); each wave stores its denom half
#pragma unroll
  for (int t = 0; t < 16; ++t)
#pragma unroll
    for (int i = 0; i < 4; ++i)
      Opart[((size_t)split * 8192 + rbase + g * 4 + i) * 512 + dh * 256 + t * 16 + ln] =
          f2bf(acc[t][i]);
  rl += __shfl_xor(rl, 16);
  rl += __shfl_xor(rl, 32);                        // sum over this wave's 16 kcols
  if (l < 16) lpart[((size_t)split * 2 + dh) * 8192 + rbase + l] = rl;
}

// ------- combine 8 partials (shared fixed max) + global/essential + final max -------
__global__ void k_combine(const u16* __restrict__ Opart, const float* __restrict__ lpart,
                          const float* __restrict__ gsc, const float* __restrict__ es,
                          const float* __restrict__ gV, const float* __restrict__ eV,
                          const float* __restrict__ mx, float* __restrict__ out) {
  const int row = blockIdx.x;
  const int tid = threadIdx.x;
  const float gs = gsc[row], e = es[row];
  const float M = fmaxf(MFIX, fmaxf(gs, e));
  const float eg = __expf(gs - M), ee = __expf(e - M);
  const float fL = __expf(MFIX - M);
  float lsum = 0.f;
#pragma unroll
  for (int s = 0; s < 8; ++s) lsum += lpart[(size_t)s * 8192 + row];
  const float inv = 1.f / (eg + ee + fL * lsum);
  for (int d = tid; d < 512; d += 256) {
    float o = 0.f;
#pragma unroll
    for (int s = 0; s < 4; ++s)
      o += bf2f(Opart[((size_t)s * 8192 + row) * 512 + d]);
    o = o * fL + eg * gV[d] + ee * eV[(size_t)row * 512 + d];
    out[(size_t)row * 512 + d] = fmaxf(o * inv, mx[(size_t)row * 512 + d]);
  }
}

// ---------------- workspace layout ----------------
static constexpr size_t OFF_XBF   = 0;
static constexpr size_t OFF_MXBF  = OFF_XBF   + (size_t)8192 * 512 * 2;
static constexpr size_t OFF_WMT   = OFF_MXBF  + (size_t)8192 * 512 * 2;
static constexpr size_t OFF_WXT   = OFF_WMT   + (size_t)1024 * 512 * 2;
static constexpr size_t OFF_LQ    = OFF_WXT   + (size_t)1024 * 512 * 2;
static constexpr size_t OFF_LK    = OFF_LQ    + (size_t)8192 * 512 * 2;
static constexpr size_t OFF_LV    = OFF_LK    + (size_t)8192 * 512 * 2;
static constexpr size_t OFF_LVT   = OFF_LV    + (size_t)8192 * 512 * 2;
static constexpr size_t OFF_EV    = OFF_LVT   + (size_t)8192 * 512 * 2;
static constexpr size_t OFF_ADJB  = OFF_EV    + (size_t)8192 * 512 * 4;
static constexpr size_t OFF_COLP  = OFF_ADJB  + (size_t)8192 * 256 * 4;
static constexpr size_t OFF_XBAR  = OFF_COLP  + (size_t)64 * 512 * 4;
static constexpr size_t OFF_GK    = OFF_XBAR  + 2048;
static constexpr size_t OFF_GV    = OFF_GK    + 2048;
static constexpr size_t OFF_WCOMB = OFF_GV    + 2048;
static constexpr size_t OFF_ES    = OFF_WCOMB + 2048;
static constexpr size_t OFF_GSC   = OFF_ES    + (size_t)8192 * 4;
static constexpr size_t OFF_OPART = OFF_GSC   + (size_t)8192 * 4;     // bf16, 4 splits
static constexpr size_t OFF_LPART = OFF_OPART + (size_t)4 * 8192 * 512 * 2;
static constexpr size_t OFF_FLAG  = OFF_LPART + (size_t)8 * 8192 * 4;
static constexpr size_t WS_NEEDED = OFF_FLAG  + 64;

extern "C" void kernel_launch(void* const* d_in, const int* in_sizes, int n_in,
                              void* d_out, int out_size, void* d_ws, size_t ws_size,
                              hipStream_t stream) {
  const u8*    adj = (const u8*)d_in[0];
  const float* x   = (const float*)d_in[1];
  const float* mx  = (const float*)d_in[2];
  const float* Wlq = (const float*)d_in[3];
  const float* Wlk = (const float*)d_in[4];
  const float* Wlv = (const float*)d_in[5];
  const float* blv = (const float*)d_in[6];
  const float* Wgq = (const float*)d_in[7];
  const float* Wgk = (const float*)d_in[8];
  const float* Wgv = (const float*)d_in[9];
  const float* bgv = (const float*)d_in[10];
  const float* Wes = (const float*)d_in[11];
  const float* Wev = (const float*)d_in[12];
  const float* bev = (const float*)d_in[13];
  float* out = (float*)d_out;

  if (ws_size < WS_NEEDED) return;

  char* ws = (char*)d_ws;
  u16*   x_bf   = (u16*)(ws + OFF_XBF);
  u16*   mx_bf  = (u16*)(ws + OFF_MXBF);
  u16*   WmT    = (u16*)(ws + OFF_WMT);
  u16*   WxT    = (u16*)(ws + OFF_WXT);
  u16*   lQ     = (u16*)(ws + OFF_LQ);
  u16*   lK     = (u16*)(ws + OFF_LK);
  u16*   lV     = (u16*)(ws + OFF_LV);
  u16*   lVT    = (u16*)(ws + OFF_LVT);
  float* eV     = (float*)(ws + OFF_EV);
  u32*   adjb   = (u32*)(ws + OFF_ADJB);
  float* colp   = (float*)(ws + OFF_COLP);
  float* xbar   = (float*)(ws + OFF_XBAR);
  float* gK     = (float*)(ws + OFF_GK);
  float* gV     = (float*)(ws + OFF_GV);
  float* wcomb  = (float*)(ws + OFF_WCOMB);
  float* es     = (float*)(ws + OFF_ES);
  float* gsc    = (float*)(ws + OFF_GSC);
  u16*   Opart  = (u16*)(ws + OFF_OPART);
  float* lpart  = (float*)(ws + OFF_LPART);
  u32*   flag   = (u32*)(ws + OFF_FLAG);

  hipMemsetAsync(flag, 0, 4, stream);
  k_adjdetect<<<1024, 256, 0, stream>>>(adj, flag);

  k_convert<<<2048, 256, 0, stream>>>(x, mx, x_bf, mx_bf);

  WtransJobs wj;
  wj.src[0] = Wlq; wj.dst[0] = WmT;
  wj.src[1] = Wev; wj.dst[1] = WmT + (size_t)512 * 512;
  wj.src[2] = Wlk; wj.dst[2] = WxT;
  wj.src[3] = Wlv; wj.dst[3] = WxT + (size_t)512 * 512;
  k_wtrans<<<dim3(16, 16, 4), dim3(32, 8), 0, stream>>>(wj);

  k_adjbits<<<8192, 256, 0, stream>>>(adj, flag, adjb);
  k_colsum<<<64, 512, 0, stream>>>(x, colp);
  k_colsum2<<<1, 512, 0, stream>>>(colp, xbar);
  k_gproj<<<2, 512, 0, stream>>>(xbar, Wgk, Wgv, bgv, gK, gV);
  k_wcomb<<<128, 256, 0, stream>>>(Wgq, gK, wcomb);
  k_esgsc<<<2048, 256, 0, stream>>>(mx, Wes, wcomb, es, gsc);

  GemmOuts o1;
  o1.obf[0] = lQ;      o1.of32[0] = nullptr; o1.bias[0] = nullptr;
  o1.obf[1] = nullptr; o1.of32[1] = eV;      o1.bias[1] = bev;
  k_gemm<<<dim3(64, 8), 256, 0, stream>>>(mx_bf, WmT, o1);

  GemmOuts o2;
  o2.obf[0] = lK; o2.of32[0] = nullptr; o2.bias[0] = nullptr;
  o2.obf[1] = lV; o2.of32[1] = nullptr; o2.bias[1] = blv;
  k_gemm<<<dim3(64, 8), 256, 0, stream>>>(x_bf, WxT, o2);

  k_vtrans<<<dim3(16, 256), dim3(32, 8), 0, stream>>>(lV, lVT);
  k_attn<<<dim3(1024), 256, 0, stream>>>(lQ, lK, lVT, adjb, Opart, lpart);
  k_combine<<<8192, 256, 0, stream>>>(Opart, lpart, gsc, es, gV, eV, mx, out);
}